// Round 8
// baseline (890.589 us; speedup 1.0000x reference)
//
#include <hip/hip_runtime.h>
#include <hip/hip_bf16.h>
#include <math.h>

#define C1N 128
#define HA 200
#define WA 200
#define HBB 100
#define WBB 360
#define GH 200
#define GW 360
#define NHD 8
#define HDD 16

typedef __attribute__((ext_vector_type(8))) short short8;
typedef __attribute__((ext_vector_type(4))) float f32x4;
typedef __attribute__((ext_vector_type(16))) float f32x16;

__device__ __forceinline__ float bf2f(unsigned short u) {
  union { unsigned int i; float f; } c; c.i = ((unsigned int)u) << 16; return c.f;
}
__device__ __forceinline__ unsigned short f2bf(float f) {
  __hip_bfloat16 h = __float2bfloat16(f);
  unsigned short u;
  __builtin_memcpy(&u, &h, sizeof(u));
  return u;
}

// ---- coordinate pipeline: must match numpy f32 op-for-op. ----
__device__ __forceinline__ void polar_xy(float fov, int i, int j, float& x, float& y) {
#pragma clang fp contract(off)
  float t = (float)j / 359.0f;
  float angle = -fov / 2.0f + fov * t;
  float ca = (float)cos((double)angle);
  float sa = (float)sin((double)angle);
  float rmax = fminf(100.0f / fabsf(ca), 100.0f / fabsf(sa));
  float r = ((float)i / 199.0f) * rmax;
  float xv = 100.0f + r * ca;
  float yv = 100.0f - r * sa;
  x = fminf(fmaxf(xv, 0.0f), 199.0f);
  y = fminf(fmaxf(yv, 0.0f), 199.0f);
}

// Fused weights in bf16: Wb[w<3] = (in_proj_w[w] @ {Wq,Wk,Wv}) ; Wb[3] = out_w.
__global__ void weff_k(const float* __restrict__ Wq, const float* __restrict__ Wk,
                       const float* __restrict__ Wv, const float* __restrict__ bq,
                       const float* __restrict__ bk, const float* __restrict__ bv,
                       const float* __restrict__ inw, const float* __restrict__ inb,
                       const float* __restrict__ outw, const float* __restrict__ outb,
                       __hip_bfloat16* __restrict__ Wb, float* __restrict__ beff) {
  int which = blockIdx.y;
  int o = blockIdx.x;
  int kcol = threadIdx.x;
  if (which == 3) {
    Wb[3 * 16384 + o * 128 + kcol] = __float2bfloat16(outw[o * 128 + kcol]);
    if (kcol == 0) beff[384 + o] = outb[o];
    return;
  }
  const float* Wx = (which == 0) ? Wq : ((which == 1) ? Wk : Wv);
  const float* bx = (which == 0) ? bq : ((which == 1) ? bk : bv);
  const float* wrow = inw + (which * 128 + o) * 128;
  float acc = 0.0f;
  for (int m = 0; m < 128; ++m) acc += wrow[m] * Wx[m * 128 + kcol];
  Wb[which * 16384 + o * 128 + kcol] = __float2bfloat16(acc);
  if (kcol == 0) {
    float bacc = inb[which * 128 + o];
    for (int m = 0; m < 128; ++m) bacc += wrow[m] * bx[m];
    beff[which * 128 + o] = bacc;
  }
}

// a (128,200,200) f32 -> aT[(y*200+x)*128 + c] bf16. LDS 32x32 tiles.
__global__ __launch_bounds__(256) void transA_k(const float* __restrict__ a,
                                                __hip_bfloat16* __restrict__ aT) {
  __shared__ float tile[32][33];
  int p0 = blockIdx.x * 32, c0 = blockIdx.y * 32;
  int tp = threadIdx.x & 31, tr = threadIdx.x >> 5;
  for (int cc = tr; cc < 32; cc += 8)
    tile[cc][tp] = a[(size_t)(c0 + cc) * 40000 + p0 + tp];
  __syncthreads();
  for (int pp = tr; pp < 32; pp += 8)
    aT[(size_t)(p0 + pp) * C1N + c0 + tp] = __float2bfloat16(tile[tp][pp]);
}

// Coalesced bilinear from aT (bf16 p-major).
__global__ __launch_bounds__(256) void bilinear2_k(const __hip_bfloat16* __restrict__ aT,
                                                   const float* __restrict__ fovp, int n,
                                                   __hip_bfloat16* __restrict__ aseq) {
  __shared__ float sw[20][4];
  __shared__ int sp[20][4];
  int j = blockIdx.x;
  int i_base = blockIdx.y * 20;
  int t = threadIdx.x;
  if (t < 20) {
    float x, y;
    polar_xy(fovp[n], i_base + t, j, x, y);
    float x0f = floorf(x), y0f = floorf(y);
    float wx = x - x0f, wy = y - y0f;
    int x0 = max(0, min(199, (int)x0f));
    int x1 = min(x0 + 1, 199);
    int y0 = max(0, min(199, (int)y0f));
    int y1 = min(y0 + 1, 199);
    sp[t][0] = y0 * 200 + x0; sp[t][1] = y0 * 200 + x1;
    sp[t][2] = y1 * 200 + x0; sp[t][3] = y1 * 200 + x1;
    sw[t][0] = (1.0f - wx) * (1.0f - wy); sw[t][1] = wx * (1.0f - wy);
    sw[t][2] = (1.0f - wx) * wy;          sw[t][3] = wx * wy;
  }
  __syncthreads();
  int lane = t & 63, wv = t >> 6;
  for (int ii = wv; ii < 20; ii += 4) {
    int i = i_base + ii;
    float w00 = sw[ii][0], w01 = sw[ii][1], w10 = sw[ii][2], w11 = sw[ii][3];
    ushort2 u00 = ((const ushort2*)(aT + (size_t)sp[ii][0] * C1N))[lane];
    ushort2 u01 = ((const ushort2*)(aT + (size_t)sp[ii][1] * C1N))[lane];
    ushort2 u10 = ((const ushort2*)(aT + (size_t)sp[ii][2] * C1N))[lane];
    ushort2 u11 = ((const ushort2*)(aT + (size_t)sp[ii][3] * C1N))[lane];
    float v0 = w00 * bf2f(u00.x) + w01 * bf2f(u01.x) + w10 * bf2f(u10.x) + w11 * bf2f(u11.x);
    float v1 = w00 * bf2f(u00.y) + w01 * bf2f(u01.y) + w10 * bf2f(u10.y) + w11 * bf2f(u11.y);
    ushort2 outv; outv.x = f2bf(v0); outv.y = f2bf(v1);
    ((ushort2*)(aseq + (size_t)(j * GH + i) * C1N))[lane] = outv;
  }
}

// b (128,100,360) -> bs[(j*100+kk)*128 + c] (bf16)
__global__ __launch_bounds__(256) void transpose_k(const float* __restrict__ b,
                                                   __hip_bfloat16* __restrict__ bs) {
  __shared__ float tile[32][33];
  int kk = blockIdx.z;
  int j0 = blockIdx.x * 32, c0 = blockIdx.y * 32;
  int tj = threadIdx.x & 31;
  int tr = threadIdx.x >> 5;
  for (int cc = tr; cc < 32; cc += 8) {
    int gj = j0 + tj;
    tile[cc][tj] = (gj < WBB) ? b[(c0 + cc) * (HBB * WBB) + kk * WBB + gj] : 0.0f;
  }
  __syncthreads();
  for (int jj = tr; jj < 32; jj += 8) {
    int gj = j0 + jj;
    if (gj < WBB)
      bs[(size_t)(gj * HBB + kk) * C1N + c0 + (threadIdx.x & 31)] =
          __float2bfloat16(tile[threadIdx.x & 31][jj]);
  }
}

// Shared MFMA core: one wave computes 16 rows x 128 cols, K=128.
__device__ __forceinline__ void gemm16_mfma(const unsigned short* __restrict__ A,
                                            const unsigned short* __restrict__ W,
                                            int m_base, f32x4 acc[8]) {
  int lane = threadIdx.x & 63;
  int col = lane & 15, quad = lane >> 4;
#pragma unroll
  for (int nt = 0; nt < 8; ++nt) acc[nt] = (f32x4)0.0f;
#pragma unroll
  for (int s = 0; s < 4; ++s) {
    short8 aF = *(const short8*)&A[(size_t)(m_base + col) * 128 + s * 32 + quad * 8];
#pragma unroll
    for (int nt = 0; nt < 8; ++nt) {
      short8 bF = *(const short8*)&W[(size_t)(nt * 16 + col) * 128 + s * 32 + quad * 8];
      acc[nt] = __builtin_amdgcn_mfma_f32_16x16x32_bf16(aF, bF, acc[nt], 0, 0, 0);
    }
  }
}

// Stage the block's 64x128 bf16 output into LDS (MFMA lane layout -> row-major).
__device__ __forceinline__ void stage_bf16(unsigned short (*tile)[136],
                                           const f32x4 acc[8],
                                           const float* __restrict__ bias) {
  int lane = threadIdx.x & 63, wv = threadIdx.x >> 6;
  int col = lane & 15, quad = lane >> 4;
#pragma unroll
  for (int nt = 0; nt < 8; ++nt) {
    float bb = bias[nt * 16 + col];
#pragma unroll
    for (int r = 0; r < 4; ++r)
      tile[wv * 16 + quad * 4 + r][nt * 16 + col] = f2bf(acc[nt][r] + bb);
  }
  __syncthreads();
}

// q' -> qb row-major bf16. M = 72000 = 1125 * 64 exactly (no tail).
__global__ __launch_bounds__(256) void gemm_q_k(const unsigned short* __restrict__ A,
                                                const unsigned short* __restrict__ Wb,
                                                const float* __restrict__ beff,
                                                unsigned short* __restrict__ qb) {
  __shared__ unsigned short tile[64][136];
  int m0 = blockIdx.x * 64;
  f32x4 acc[8];
  gemm16_mfma(A, Wb, m0 + (threadIdx.x >> 6) * 16, acc);
  stage_bf16(tile, acc, beff);
  for (int u = threadIdx.x; u < 1024; u += 256) {
    int rl = u >> 4, ch = (u & 15) * 8;
    *(short8*)&qb[(size_t)(m0 + rl) * 128 + ch] = *(const short8*)&tile[rl][ch];
  }
}

// k' -> kb [j][key(pad128)][col] and v' -> vT [j][col][key(pad128)], fused.
// Grid (563, 2); M = 36000. Tail A-reads stay inside P1 (36096 rows); poison
// benign. Stores only touch real keys; kb/vT pad keys keep benign poison
// (vT pads feed PV MFMA via P=0 — NaN hazard if ever overwritten; nothing
// writes them now that avgb lives entirely inside dead qb).
__global__ __launch_bounds__(256) void gemm_kv_k(const unsigned short* __restrict__ A,
                                                 const unsigned short* __restrict__ Wb,
                                                 const float* __restrict__ beff,
                                                 unsigned short* __restrict__ kb,
                                                 unsigned short* __restrict__ vT) {
  __shared__ unsigned short tile[64][136];
  int which = blockIdx.y;
  int m0 = blockIdx.x * 64;
  f32x4 acc[8];
  gemm16_mfma(A, Wb + (which ? 32768 : 16384), m0 + (threadIdx.x >> 6) * 16, acc);
  stage_bf16(tile, acc, beff + (which ? 256 : 128));
  if (which == 0) {
    for (int u = threadIdx.x; u < 1024; u += 256) {
      int rl = u >> 4, ch = (u & 15) * 8;
      int row = m0 + rl;
      if (row < 36000) {
        int jj = row / 100, key = row - jj * 100;
        *(short8*)&kb[((size_t)jj * 128 + key) * 128 + ch] = *(const short8*)&tile[rl][ch];
      }
    }
  } else {
    for (int u = threadIdx.x; u < 8192; u += 256) {
      int cc = u >> 6, kl = u & 63;
      int row = m0 + kl;
      if (row < 36000) {
        int jj = row / 100, key = row - jj * 100;
        vT[((size_t)jj * 128 + cc) * 128 + key] = tile[kl][cc];
      }
    }
  }
}

// MFMA attention v6: 8 waves = 8 heads per (j, mt) block, XCD-aware remap.
__global__ __launch_bounds__(512) void attn6_k(const unsigned short* __restrict__ qb,
                                               const unsigned short* __restrict__ kb,
                                               const unsigned short* __restrict__ vT,
                                               unsigned short* __restrict__ o) {
  __shared__ unsigned short Ps[8][32][120];  // 61440 B
  __shared__ unsigned short Osh[32][136];    // 8704 B
  int d = blockIdx.x;
  int xcd = d & 7, idx = d >> 3;            // idx in [0,315)
  int j = xcd * 45 + idx % 45;              // all 7 mt of a j share d%8 -> XCD
  int mt = idx / 45;
  int h = threadIdx.x >> 6;
  int lane = threadIdx.x & 63;
  int col = lane & 31, half = lane >> 5;

  short8 qF = *(const short8*)&qb[(size_t)(j * 200 + mt * 32 + col) * 128 + h * 16 + half * 8];
  f32x16 S[4];
#pragma unroll
  for (int nt = 0; nt < 4; ++nt) {
    short8 kF = *(const short8*)&kb[((size_t)j * 128 + nt * 32 + col) * 128 + h * 16 + half * 8];
    S[nt] = __builtin_amdgcn_mfma_f32_32x32x16_bf16(kF, qF, (f32x16)0.0f, 0, 0, 0);
  }

  float rsum = 0.0f;
#pragma unroll
  for (int nt = 0; nt < 3; ++nt)
#pragma unroll
    for (int r = 0; r < 16; ++r) {
      float e = __expf(S[nt][r] * 0.25f);
      S[nt][r] = e; rsum += e;
    }
#pragma unroll
  for (int r = 0; r < 16; ++r) {
    float e = (half == 0 && r < 4) ? __expf(S[3][r] * 0.25f) : 0.0f;
    S[3][r] = e; rsum += e;
  }
  rsum += __shfl_xor(rsum, 32, 64);
  float inv = __fdividef(1.0f, rsum);

#pragma unroll
  for (int nt = 0; nt < 4; ++nt) {
#pragma unroll
    for (int g = 0; g < 4; ++g) {
      if (nt == 3 && g >= 2) continue;  // keys 112..127 never read by PV
      float e0 = S[nt][4 * g + 0] * inv, e1 = S[nt][4 * g + 1] * inv;
      float e2 = S[nt][4 * g + 2] * inv, e3 = S[nt][4 * g + 3] * inv;
      unsigned int lo, hi;
      asm("v_cvt_pk_bf16_f32 %0, %1, %2" : "=v"(lo) : "v"(e0), "v"(e1));
      asm("v_cvt_pk_bf16_f32 %0, %1, %2" : "=v"(hi) : "v"(e2), "v"(e3));
      *(uint2*)&Ps[h][col][nt * 32 + 8 * g + 4 * half] = make_uint2(lo, hi);
    }
  }

  short8 ones;
#pragma unroll
  for (int i = 0; i < 8; ++i) ones[i] = (short)0x3F80;
  const unsigned short* vrow = &vT[((size_t)j * 128 + h * 16 + (col & 15)) * 128];
  f32x16 O = (f32x16)0.0f;
#pragma unroll
  for (int ks = 0; ks < 7; ++ks) {
    short8 aP = *(const short8*)&Ps[h][col][ks * 16 + half * 8];
    short8 bV = (col < 16) ? *(const short8*)&vrow[ks * 16 + half * 8] : ones;
    O = __builtin_amdgcn_mfma_f32_32x32x16_bf16(aP, bV, O, 0, 0, 0);
  }
#pragma unroll
  for (int r = 0; r < 16; ++r) {
    int row = (r & 3) + 8 * (r >> 2) + 4 * half;
    if (col < 16) Osh[row][h * 16 + col] = f2bf(O[r]);
  }
  __syncthreads();
  int rl = threadIdx.x >> 4, ch = (threadIdx.x & 15) * 8;
  int qr = mt * 32 + rl;
  if (qr < 200)
    *(short8*)&o[(size_t)(j * 200 + qr) * 128 + ch] = *(const short8*)&Osh[rl][ch];
}

// ---- CSR inverse map (int atomics only; 72K + 72K) ----
__global__ __launch_bounds__(256) void count_k(const float* __restrict__ fovp, int n,
                                               int* __restrict__ pid,
                                               int* __restrict__ counts) {
  int m = blockIdx.x * 256 + threadIdx.x;
  if (m >= 72000) return;
  int j = m / 200, i = m - j * 200;
  float x, y;
  polar_xy(fovp[n], i, j, x, y);
  int xi = (int)rintf(x); xi = max(0, min(199, xi));
  int yi = (int)rintf(y); yi = max(0, min(199, yi));
  int p = yi * 200 + xi;
  pid[m] = p;
  atomicAdd(counts + p, 1);
}

// scan_k: single block 1024 threads; exclusive scan of counts[40000].
// Thread t owns 40 contiguous elements; 1024 partials scanned serially by t0.
__global__ __launch_bounds__(1024) void scan_k(const int* __restrict__ counts,
                                               int* __restrict__ offs,
                                               int* __restrict__ cursor) {
  __shared__ int tsum[1024];
  int t = threadIdx.x;
  int base = t * 40;
  int s = 0;
  for (int u = 0; u < 40; ++u) {
    int idx = base + u;
    if (idx < 40000) s += counts[idx];
  }
  tsum[t] = s;
  __syncthreads();
  if (t == 0) {
    int run = 0;
    for (int u = 0; u < 1024; ++u) { int v = tsum[u]; tsum[u] = run; run += v; }
  }
  __syncthreads();
  int run = tsum[t];
  for (int u = 0; u < 40; ++u) {
    int idx = base + u;
    if (idx < 40000) {
      offs[idx] = run; cursor[idx] = run;
      run += counts[idx];
    }
  }
}

// fill_k: bump-allocate slots; srcm lists each pixel's source rows contiguously.
__global__ __launch_bounds__(256) void fill_k(const int* __restrict__ pid,
                                              int* __restrict__ cursor,
                                              int* __restrict__ srcm) {
  int m = blockIdx.x * 256 + threadIdx.x;
  if (m >= 72000) return;
  int slot = atomicAdd(cursor + pid[m], 1);
  srcm[slot] = m;
}

// gather2_k: balanced, zero f32 atomics. Block = 16 pixels; ALL 4 waves
// cooperate on EVERY pixel (wave s owns the s-th quarter of its source list)
// -> center hot-spot (~450 rows) costs ~110 rows/wave inside one block, not
// 450 serial in one wave (round-7 straggler: 110us @ 5% occupancy).
// Sums o rows (bf16, 256B/row via 64 lanes x ushort2) in f32, combines via
// LDS, writes avg (bf16) exactly once per pixel. cnt=0 -> avg=0.
__global__ __launch_bounds__(256) void gather2_k(const unsigned short* __restrict__ o,
                                                 const int* __restrict__ offs,
                                                 const int* __restrict__ counts,
                                                 const int* __restrict__ srcm,
                                                 unsigned short* __restrict__ avgb) {
  __shared__ float part[16][4][128];  // 32 KB
  int wv = threadIdx.x >> 6, lane = threadIdx.x & 63;
  int pbase = blockIdx.x * 16;
  for (int k = 0; k < 16; ++k) {
    int p = pbase + k;
    int nsz = counts[p], s0 = offs[p];
    int q0 = (nsz * wv) >> 2, q1 = (nsz * (wv + 1)) >> 2;
    float sx = 0.0f, sy = 0.0f;
    for (int qb_ = q0; qb_ < q1; qb_ += 8) {
      const unsigned short* rp[8];
      int nb = q1 - qb_;
#pragma unroll
      for (int u = 0; u < 8; ++u) {
        int q = min(qb_ + u, q1 - 1);
        rp[u] = o + (size_t)srcm[s0 + q] * 128 + 2 * lane;
      }
#pragma unroll
      for (int u = 0; u < 8; ++u) {
        ushort2 r = *(const ushort2*)rp[u];
        if (u < nb) { sx += bf2f(r.x); sy += bf2f(r.y); }
      }
    }
    part[k][wv][2 * lane] = sx;
    part[k][wv][2 * lane + 1] = sy;
  }
  __syncthreads();
  for (int u = threadIdx.x; u < 2048; u += 256) {
    int k = u >> 7, c = u & 127;
    int p = pbase + k;
    int nsz = counts[p];
    float s = part[k][0][c] + part[k][1][c] + part[k][2][c] + part[k][3][c];
    float inv = (nsz > 0) ? 1.0f / (float)nsz : 0.0f;
    avgb[(size_t)p * 128 + c] = f2bf(s * inv);
  }
}

// gemm_ar_k: res = avg @ Wout^T + bias (linearity: avg of o rows then GEMM ==
// avg of aenh rows), fused with the final add: out[c][p] = a[c][p] +
// (cnt[p]>0 ? res[p][c] : 0).  M = 40000 = 625*64 exactly. Replaces gemm_o
// (72000 rows) + aenh round-trip + finalize pass.
__global__ __launch_bounds__(256) void gemm_ar_k(const unsigned short* __restrict__ A,
                                                 const unsigned short* __restrict__ Wb,
                                                 const float* __restrict__ beff,
                                                 const int* __restrict__ counts,
                                                 const float* __restrict__ a,
                                                 float* __restrict__ out) {
  __shared__ float tile[64][132];
  __shared__ int scnt[64];
  int m0 = blockIdx.x * 64;
  int t = threadIdx.x;
  f32x4 acc[8];
  gemm16_mfma(A, Wb + 49152, m0 + (t >> 6) * 16, acc);
  if (t < 64) scnt[t] = counts[m0 + t];
  {
    int lane = t & 63, wv = t >> 6;
    int col = lane & 15, quad = lane >> 4;
#pragma unroll
    for (int nt = 0; nt < 8; ++nt) {
      float bb = beff[384 + nt * 16 + col];
#pragma unroll
      for (int r = 0; r < 4; ++r)
        tile[wv * 16 + quad * 4 + r][nt * 16 + col] = acc[nt][r] + bb;
    }
  }
  __syncthreads();
  // out c-major: consecutive threads -> consecutive p (256B segments).
  for (int u = t; u < 8192; u += 256) {
    int pp = u & 63, c = u >> 6;
    int g = c * 40000 + m0 + pp;
    float v = (scnt[pp] > 0) ? tile[pp][c] : 0.0f;
    out[g] = a[g] + v;
  }
}

extern "C" void kernel_launch(void* const* d_in, const int* in_sizes, int n_in,
                              void* d_out, int out_size, void* d_ws, size_t ws_size,
                              hipStream_t stream) {
  const float* list_a = (const float*)d_in[0];
  const float* list_b = (const float*)d_in[1];
  const float* fov   = (const float*)d_in[2];
  const float* Wq    = (const float*)d_in[5];
  const float* bq    = (const float*)d_in[6];
  const float* Wk    = (const float*)d_in[7];
  const float* bk    = (const float*)d_in[8];
  const float* Wv    = (const float*)d_in[9];
  const float* bv    = (const float*)d_in[10];
  const float* inw   = (const float*)d_in[11];
  const float* inb   = (const float*)d_in[12];
  const float* outw  = (const float*)d_in[13];
  const float* outb  = (const float*)d_in[14];
  float* out = (float*)d_out;
  float* ws = (float*)d_ws;

  // Layout (float units):
  // beff 512 | Wb 32768 | P2 9,216,000 (aT) | qb 4,620,288 | kb 2,949,120
  // | vT 2,949,120 | P0 4,620,288 (a_seq/o bf16) | P1 2,310,144 (b_seq bf16;
  // CSR ints after gemm_kv).
  // avgb (40000x128 bf16 = 2,560,000 floats) overlays dead qb ONLY (qb region
  // is 4.6M floats) -> kb/vT untouched; their pad keys keep benign poison
  // (vT pads feed PV MFMA: NaN-reinterp hazard).
  float* beff = ws;
  __hip_bfloat16* Wb = (__hip_bfloat16*)(ws + 512);
  float* P2 = ws + 512 + 32768;
  float* qb_f = P2 + 9216000;
  float* kb_f = qb_f + 4620288;
  float* vT_f = kb_f + 2949120;
  float* P0_f = vT_f + 2949120;
  float* P1_f = P0_f + 4620288;

  unsigned short* qb = (unsigned short*)qb_f;
  unsigned short* kb = (unsigned short*)kb_f;
  unsigned short* vT = (unsigned short*)vT_f;
  __hip_bfloat16* P0 = (__hip_bfloat16*)P0_f;
  __hip_bfloat16* P1 = (__hip_bfloat16*)P1_f;
  __hip_bfloat16* aT = (__hip_bfloat16*)P2;     // dead after bilinear2
  unsigned short* avgb = (unsigned short*)qb_f; // over dead qb (after attn6)

  // CSR arrays in P1 (b_seq dead after gemm_kv, rebuilt next sample):
  int* pid    = (int*)P1_f;          // 72000
  int* counts = pid + 72000;         // 40000
  int* offs   = counts + 40000;      // 40000
  int* cursor = offs + 40000;        // 40000
  int* srcm   = cursor + 40000;      // 72000   (total 264,000 ints << P1)

  weff_k<<<dim3(128, 4), 128, 0, stream>>>(Wq, Wk, Wv, bq, bk, bv, inw, inb, outw, outb, Wb, beff);

  for (int n = 0; n < 2; ++n) {
    const float* a_n = list_a + (size_t)n * C1N * HA * WA;
    const float* b_n = list_b + (size_t)n * C1N * HBB * WBB;
    float* out_n = out + (size_t)n * C1N * HA * WA;

    transA_k<<<dim3(1250, 4), 256, 0, stream>>>(a_n, aT);
    bilinear2_k<<<dim3(GW, 10), 256, 0, stream>>>(aT, fov, n, P0);
    transpose_k<<<dim3(12, 4, 100), 256, 0, stream>>>(b_n, P1);
    gemm_kv_k<<<dim3(563, 2), 256, 0, stream>>>((const unsigned short*)P1,
                                                (const unsigned short*)Wb, beff, kb, vT);
    // ---- CSR build (P1 dead until next sample's transpose) ----
    (void)hipMemsetAsync(counts, 0, 40000 * sizeof(int), stream);
    count_k<<<282, 256, 0, stream>>>(fov, n, pid, counts);
    scan_k<<<1, 1024, 0, stream>>>(counts, offs, cursor);
    fill_k<<<282, 256, 0, stream>>>(pid, cursor, srcm);

    gemm_q_k<<<1125, 256, 0, stream>>>((const unsigned short*)P0,
                                       (const unsigned short*)Wb, beff, qb);
    attn6_k<<<2520, 512, 0, stream>>>(qb, kb, vT, (unsigned short*)P0);   // o -> P0
    gather2_k<<<2500, 256, 0, stream>>>((const unsigned short*)P0, offs, counts,
                                        srcm, avgb);                      // o-avg, no atomics
    gemm_ar_k<<<625, 256, 0, stream>>>(avgb, (const unsigned short*)Wb, beff,
                                       counts, a_n, out_n);               // + a, write out
  }
}

// Round 9
// 506.148 us; speedup vs baseline: 1.7595x; 1.7595x over previous
//
#include <hip/hip_runtime.h>
#include <hip/hip_bf16.h>
#include <math.h>

#define C1N 128
#define HA 200
#define WA 200
#define HBB 100
#define WBB 360
#define GH 200
#define GW 360
#define NHD 8
#define HDD 16

typedef __attribute__((ext_vector_type(8))) short short8;
typedef __attribute__((ext_vector_type(4))) float f32x4;
typedef __attribute__((ext_vector_type(16))) float f32x16;

__device__ __forceinline__ float bf2f(unsigned short u) {
  union { unsigned int i; float f; } c; c.i = ((unsigned int)u) << 16; return c.f;
}
__device__ __forceinline__ unsigned short f2bf(float f) {
  __hip_bfloat16 h = __float2bfloat16(f);
  unsigned short u;
  __builtin_memcpy(&u, &h, sizeof(u));
  return u;
}

// ---- coordinate pipeline: must match numpy f32 op-for-op. ----
__device__ __forceinline__ void polar_xy(float fov, int i, int j, float& x, float& y) {
#pragma clang fp contract(off)
  float t = (float)j / 359.0f;
  float angle = -fov / 2.0f + fov * t;
  float ca = (float)cos((double)angle);
  float sa = (float)sin((double)angle);
  float rmax = fminf(100.0f / fabsf(ca), 100.0f / fabsf(sa));
  float r = ((float)i / 199.0f) * rmax;
  float xv = 100.0f + r * ca;
  float yv = 100.0f - r * sa;
  x = fminf(fmaxf(xv, 0.0f), 199.0f);
  y = fminf(fmaxf(yv, 0.0f), 199.0f);
}

// Fused weights in bf16: Wb[w<3] = (in_proj_w[w] @ {Wq,Wk,Wv}) ; Wb[3] = out_w.
__global__ void weff_k(const float* __restrict__ Wq, const float* __restrict__ Wk,
                       const float* __restrict__ Wv, const float* __restrict__ bq,
                       const float* __restrict__ bk, const float* __restrict__ bv,
                       const float* __restrict__ inw, const float* __restrict__ inb,
                       const float* __restrict__ outw, const float* __restrict__ outb,
                       __hip_bfloat16* __restrict__ Wb, float* __restrict__ beff) {
  int which = blockIdx.y;
  int o = blockIdx.x;
  int kcol = threadIdx.x;
  if (which == 3) {
    Wb[3 * 16384 + o * 128 + kcol] = __float2bfloat16(outw[o * 128 + kcol]);
    if (kcol == 0) beff[384 + o] = outb[o];
    return;
  }
  const float* Wx = (which == 0) ? Wq : ((which == 1) ? Wk : Wv);
  const float* bx = (which == 0) ? bq : ((which == 1) ? bk : bv);
  const float* wrow = inw + (which * 128 + o) * 128;
  float acc = 0.0f;
  for (int m = 0; m < 128; ++m) acc += wrow[m] * Wx[m * 128 + kcol];
  Wb[which * 16384 + o * 128 + kcol] = __float2bfloat16(acc);
  if (kcol == 0) {
    float bacc = inb[which * 128 + o];
    for (int m = 0; m < 128; ++m) bacc += wrow[m] * bx[m];
    beff[which * 128 + o] = bacc;
  }
}

// a (128,200,200) f32 -> aT[(y*200+x)*128 + c] bf16. LDS 32x32 tiles.
__global__ __launch_bounds__(256) void transA_k(const float* __restrict__ a,
                                                __hip_bfloat16* __restrict__ aT) {
  __shared__ float tile[32][33];
  int p0 = blockIdx.x * 32, c0 = blockIdx.y * 32;
  int tp = threadIdx.x & 31, tr = threadIdx.x >> 5;
  for (int cc = tr; cc < 32; cc += 8)
    tile[cc][tp] = a[(size_t)(c0 + cc) * 40000 + p0 + tp];
  __syncthreads();
  for (int pp = tr; pp < 32; pp += 8)
    aT[(size_t)(p0 + pp) * C1N + c0 + tp] = __float2bfloat16(tile[tp][pp]);
}

// Coalesced bilinear from aT (bf16 p-major).
__global__ __launch_bounds__(256) void bilinear2_k(const __hip_bfloat16* __restrict__ aT,
                                                   const float* __restrict__ fovp, int n,
                                                   __hip_bfloat16* __restrict__ aseq) {
  __shared__ float sw[20][4];
  __shared__ int sp[20][4];
  int j = blockIdx.x;
  int i_base = blockIdx.y * 20;
  int t = threadIdx.x;
  if (t < 20) {
    float x, y;
    polar_xy(fovp[n], i_base + t, j, x, y);
    float x0f = floorf(x), y0f = floorf(y);
    float wx = x - x0f, wy = y - y0f;
    int x0 = max(0, min(199, (int)x0f));
    int x1 = min(x0 + 1, 199);
    int y0 = max(0, min(199, (int)y0f));
    int y1 = min(y0 + 1, 199);
    sp[t][0] = y0 * 200 + x0; sp[t][1] = y0 * 200 + x1;
    sp[t][2] = y1 * 200 + x0; sp[t][3] = y1 * 200 + x1;
    sw[t][0] = (1.0f - wx) * (1.0f - wy); sw[t][1] = wx * (1.0f - wy);
    sw[t][2] = (1.0f - wx) * wy;          sw[t][3] = wx * wy;
  }
  __syncthreads();
  int lane = t & 63, wv = t >> 6;
  for (int ii = wv; ii < 20; ii += 4) {
    int i = i_base + ii;
    float w00 = sw[ii][0], w01 = sw[ii][1], w10 = sw[ii][2], w11 = sw[ii][3];
    ushort2 u00 = ((const ushort2*)(aT + (size_t)sp[ii][0] * C1N))[lane];
    ushort2 u01 = ((const ushort2*)(aT + (size_t)sp[ii][1] * C1N))[lane];
    ushort2 u10 = ((const ushort2*)(aT + (size_t)sp[ii][2] * C1N))[lane];
    ushort2 u11 = ((const ushort2*)(aT + (size_t)sp[ii][3] * C1N))[lane];
    float v0 = w00 * bf2f(u00.x) + w01 * bf2f(u01.x) + w10 * bf2f(u10.x) + w11 * bf2f(u11.x);
    float v1 = w00 * bf2f(u00.y) + w01 * bf2f(u01.y) + w10 * bf2f(u10.y) + w11 * bf2f(u11.y);
    ushort2 outv; outv.x = f2bf(v0); outv.y = f2bf(v1);
    ((ushort2*)(aseq + (size_t)(j * GH + i) * C1N))[lane] = outv;
  }
}

// b (128,100,360) -> bs[(j*100+kk)*128 + c] (bf16)
__global__ __launch_bounds__(256) void transpose_k(const float* __restrict__ b,
                                                   __hip_bfloat16* __restrict__ bs) {
  __shared__ float tile[32][33];
  int kk = blockIdx.z;
  int j0 = blockIdx.x * 32, c0 = blockIdx.y * 32;
  int tj = threadIdx.x & 31;
  int tr = threadIdx.x >> 5;
  for (int cc = tr; cc < 32; cc += 8) {
    int gj = j0 + tj;
    tile[cc][tj] = (gj < WBB) ? b[(c0 + cc) * (HBB * WBB) + kk * WBB + gj] : 0.0f;
  }
  __syncthreads();
  for (int jj = tr; jj < 32; jj += 8) {
    int gj = j0 + jj;
    if (gj < WBB)
      bs[(size_t)(gj * HBB + kk) * C1N + c0 + (threadIdx.x & 31)] =
          __float2bfloat16(tile[threadIdx.x & 31][jj]);
  }
}

// Shared MFMA core: one wave computes 16 rows x 128 cols, K=128.
__device__ __forceinline__ void gemm16_mfma(const unsigned short* __restrict__ A,
                                            const unsigned short* __restrict__ W,
                                            int m_base, f32x4 acc[8]) {
  int lane = threadIdx.x & 63;
  int col = lane & 15, quad = lane >> 4;
#pragma unroll
  for (int nt = 0; nt < 8; ++nt) acc[nt] = (f32x4)0.0f;
#pragma unroll
  for (int s = 0; s < 4; ++s) {
    short8 aF = *(const short8*)&A[(size_t)(m_base + col) * 128 + s * 32 + quad * 8];
#pragma unroll
    for (int nt = 0; nt < 8; ++nt) {
      short8 bF = *(const short8*)&W[(size_t)(nt * 16 + col) * 128 + s * 32 + quad * 8];
      acc[nt] = __builtin_amdgcn_mfma_f32_16x16x32_bf16(aF, bF, acc[nt], 0, 0, 0);
    }
  }
}

// Stage the block's 64x128 bf16 output into LDS (MFMA lane layout -> row-major).
__device__ __forceinline__ void stage_bf16(unsigned short (*tile)[136],
                                           const f32x4 acc[8],
                                           const float* __restrict__ bias) {
  int lane = threadIdx.x & 63, wv = threadIdx.x >> 6;
  int col = lane & 15, quad = lane >> 4;
#pragma unroll
  for (int nt = 0; nt < 8; ++nt) {
    float bb = bias[nt * 16 + col];
#pragma unroll
    for (int r = 0; r < 4; ++r)
      tile[wv * 16 + quad * 4 + r][nt * 16 + col] = f2bf(acc[nt][r] + bb);
  }
  __syncthreads();
}

// k' -> kb [j][key(pad128)][col] and v' -> vT [j][col][key(pad128)], fused.
// Grid (563, 2); M = 36000. Tail A-reads stay inside P1 (36096 rows); poison
// benign. Stores only touch real keys; kb/vT pad keys keep benign poison
// (vT pads feed PV MFMA via P=0 — NaN-reinterp hazard if overwritten).
__global__ __launch_bounds__(256) void gemm_kv_k(const unsigned short* __restrict__ A,
                                                 const unsigned short* __restrict__ Wb,
                                                 const float* __restrict__ beff,
                                                 unsigned short* __restrict__ kb,
                                                 unsigned short* __restrict__ vT) {
  __shared__ unsigned short tile[64][136];
  int which = blockIdx.y;
  int m0 = blockIdx.x * 64;
  f32x4 acc[8];
  gemm16_mfma(A, Wb + (which ? 32768 : 16384), m0 + (threadIdx.x >> 6) * 16, acc);
  stage_bf16(tile, acc, beff + (which ? 256 : 128));
  if (which == 0) {
    for (int u = threadIdx.x; u < 1024; u += 256) {
      int rl = u >> 4, ch = (u & 15) * 8;
      int row = m0 + rl;
      if (row < 36000) {
        int jj = row / 100, key = row - jj * 100;
        *(short8*)&kb[((size_t)jj * 128 + key) * 128 + ch] = *(const short8*)&tile[rl][ch];
      }
    }
  } else {
    for (int u = threadIdx.x; u < 8192; u += 256) {
      int cc = u >> 6, kl = u & 63;
      int row = m0 + kl;
      if (row < 36000) {
        int jj = row / 100, key = row - jj * 100;
        vT[((size_t)jj * 128 + cc) * 128 + key] = tile[kl][cc];
      }
    }
  }
}

// MFMA attention v7 = attn6 + FUSED q-projection (gemm_q deleted).
// Block = 512 thr = 8 waves = (j, mt); wave h = head h. Grid 2520 1D with
// XCD-aware remap (all 7 mt of a j share d%8 -> same XCD L2).
// Phase 0 (new): q' = a_seq[32 rows] @ Wq_eff^T + bq staged into qTile LDS.
//   Zero redundancy: this (j,mt) q-tile is used only by this block. Each wave
//   computes 16 rows x 32 cols (8 MFMA). a_seq is read AND o written in-place
//   (P0): each row belongs to exactly one block; intra-block RAW ordered by
//   this block's own barriers. mt=6 reads rows 200..223 of j = rows of j+1
//   (a_seq or already-written o: finite bf16, benign) -> results discarded by
//   the qr<200 store guard (same hazard class attn6 had via qb).
// Osh aliases qTile (qTile dead after the post-stage barrier reads; an extra
// barrier precedes Osh writes). LDS total unchanged: 61440 + 8704 = 70144.
__global__ __launch_bounds__(512) void attn7_k(unsigned short* __restrict__ aseq_o,
                                               const unsigned short* __restrict__ kb,
                                               const unsigned short* __restrict__ vT,
                                               const unsigned short* __restrict__ Wb,
                                               const float* __restrict__ beff) {
  __shared__ unsigned short Ps[8][32][120];  // 61440 B
  __shared__ unsigned short qos[32][136];    // 8704 B: qTile, then Osh
  int d = blockIdx.x;
  int xcd = d & 7, idx = d >> 3;            // idx in [0,315)
  int j = xcd * 45 + idx % 45;
  int mt = idx / 45;
  int h = threadIdx.x >> 6;
  int lane = threadIdx.x & 63;
  int col = lane & 31, half = lane >> 5;
  int col16 = lane & 15, quad = lane >> 4;

  // ---- phase 0: fused q-projection into qos (as qTile) ----
  {
    int rs = h & 1;                  // row strip: rows rs*16 .. +16
    int ng = h >> 1;                 // col group: nt = ng*2 + {0,1}
    int m_base = j * 200 + mt * 32 + rs * 16;
    f32x4 qacc[2];
    qacc[0] = (f32x4)0.0f; qacc[1] = (f32x4)0.0f;
#pragma unroll
    for (int s = 0; s < 4; ++s) {
      short8 aF = *(const short8*)&aseq_o[(size_t)(m_base + col16) * 128 + s * 32 + quad * 8];
#pragma unroll
      for (int i = 0; i < 2; ++i) {
        int nt = ng * 2 + i;
        short8 bF = *(const short8*)&Wb[(size_t)(nt * 16 + col16) * 128 + s * 32 + quad * 8];
        qacc[i] = __builtin_amdgcn_mfma_f32_16x16x32_bf16(aF, bF, qacc[i], 0, 0, 0);
      }
    }
#pragma unroll
    for (int i = 0; i < 2; ++i) {
      int nt = ng * 2 + i;
      float bb = beff[nt * 16 + col16];
#pragma unroll
      for (int r = 0; r < 4; ++r)
        qos[rs * 16 + quad * 4 + r][nt * 16 + col16] = f2bf(qacc[i][r] + bb);
    }
  }
  __syncthreads();

  // ---- S' = K Q^T (A: key rows, B: q rows; K=16=head_dim) ----
  short8 qF = *(const short8*)&qos[col][h * 16 + half * 8];
  f32x16 S[4];
#pragma unroll
  for (int nt = 0; nt < 4; ++nt) {
    short8 kF = *(const short8*)&kb[((size_t)j * 128 + nt * 32 + col) * 128 + h * 16 + half * 8];
    S[nt] = __builtin_amdgcn_mfma_f32_32x32x16_bf16(kF, qF, (f32x16)0.0f, 0, 0, 0);
  }

  float rsum = 0.0f;
#pragma unroll
  for (int nt = 0; nt < 3; ++nt)
#pragma unroll
    for (int r = 0; r < 16; ++r) {
      float e = __expf(S[nt][r] * 0.25f);
      S[nt][r] = e; rsum += e;
    }
#pragma unroll
  for (int r = 0; r < 16; ++r) {
    float e = (half == 0 && r < 4) ? __expf(S[3][r] * 0.25f) : 0.0f;
    S[3][r] = e; rsum += e;
  }
  rsum += __shfl_xor(rsum, 32, 64);
  float inv = __fdividef(1.0f, rsum);

#pragma unroll
  for (int nt = 0; nt < 4; ++nt) {
#pragma unroll
    for (int g = 0; g < 4; ++g) {
      if (nt == 3 && g >= 2) continue;  // keys 112..127 never read by PV
      float e0 = S[nt][4 * g + 0] * inv, e1 = S[nt][4 * g + 1] * inv;
      float e2 = S[nt][4 * g + 2] * inv, e3 = S[nt][4 * g + 3] * inv;
      unsigned int lo, hi;
      asm("v_cvt_pk_bf16_f32 %0, %1, %2" : "=v"(lo) : "v"(e0), "v"(e1));
      asm("v_cvt_pk_bf16_f32 %0, %1, %2" : "=v"(hi) : "v"(e2), "v"(e3));
      *(uint2*)&Ps[h][col][nt * 32 + 8 * g + 4 * half] = make_uint2(lo, hi);
    }
  }

  short8 ones;
#pragma unroll
  for (int i = 0; i < 8; ++i) ones[i] = (short)0x3F80;
  const unsigned short* vrow = &vT[((size_t)j * 128 + h * 16 + col16) * 128];
  f32x16 O = (f32x16)0.0f;
#pragma unroll
  for (int ks = 0; ks < 7; ++ks) {
    short8 aP = *(const short8*)&Ps[h][col][ks * 16 + half * 8];
    short8 bV = (col < 16) ? *(const short8*)&vrow[ks * 16 + half * 8] : ones;
    O = __builtin_amdgcn_mfma_f32_32x32x16_bf16(aP, bV, O, 0, 0, 0);
  }
  // qTile fully consumed (qF read right after stage barrier); reuse as Osh.
  __syncthreads();
#pragma unroll
  for (int r = 0; r < 16; ++r) {
    int row = (r & 3) + 8 * (r >> 2) + 4 * half;
    if (col < 16) qos[row][h * 16 + col] = f2bf(O[r]);
  }
  __syncthreads();
  int rl = threadIdx.x >> 4, ch = (threadIdx.x & 15) * 8;
  int qr = mt * 32 + rl;
  if (qr < 200)
    *(short8*)&aseq_o[(size_t)(j * 200 + qr) * 128 + ch] = *(const short8*)&qos[rl][ch];
}

// Fused out-projection + scatter: C = o @ Wout^T + b into an LDS f32 tile,
// pixel indices per row (each row evaluated exactly once), cnt bumped, then a
// run-merged atomicAdd walk over the LDS tile into accP (p-major).
// M = 72000 = 1125*64 (no tail). accP lives in P2 (aT dead; never aliases A).
__global__ __launch_bounds__(256) void gemm_os_k(const unsigned short* __restrict__ A,
                                                 const unsigned short* __restrict__ Wb,
                                                 const float* __restrict__ beff,
                                                 const float* __restrict__ fovp, int n,
                                                 float* __restrict__ accP,
                                                 float* __restrict__ cnt) {
  __shared__ float tile[64][132];
  __shared__ int sidx[64];
  int m0 = blockIdx.x * 64;
  int t = threadIdx.x;
  f32x4 acc[8];
  gemm16_mfma(A, Wb + 49152, m0 + (t >> 6) * 16, acc);
  if (t < 64) {
    int m = m0 + t;
    int j = m / 200, i = m - j * 200;
    float x, y;
    polar_xy(fovp[n], i, j, x, y);
    int xi = (int)rintf(x); xi = max(0, min(199, xi));
    int yi = (int)rintf(y); yi = max(0, min(199, yi));
    sidx[t] = yi * 200 + xi;
    atomicAdd(&cnt[yi * 200 + xi], 1.0f);
  }
  {
    int lane = t & 63, wv = t >> 6;
    int col = lane & 15, quad = lane >> 4;
#pragma unroll
    for (int nt = 0; nt < 8; ++nt) {
      float bb = beff[384 + nt * 16 + col];
#pragma unroll
      for (int r = 0; r < 4; ++r)
        tile[wv * 16 + quad * 4 + r][nt * 16 + col] = acc[nt][r] + bb;
    }
  }
  __syncthreads();
  int c = t & 127, half = t >> 7;
  int r0 = half * 32;
  int cur = sidx[r0];
  float sum = 0.0f;
#pragma unroll 4
  for (int r = r0; r < r0 + 32; ++r) {
    float v = tile[r][c];
    int idx = sidx[r];
    if (idx != cur) {
      atomicAdd(&accP[(size_t)cur * C1N + c], sum);
      cur = idx;
      sum = v;
    } else {
      sum += v;
    }
  }
  atomicAdd(&accP[(size_t)cur * C1N + c], sum);
}

// out = a + accP/cnt (LDS transpose, coalesced both sides).
__global__ __launch_bounds__(256) void finalize2_k(const float* __restrict__ a,
                                                   const float* __restrict__ accP,
                                                   const float* __restrict__ cnt,
                                                   float* __restrict__ out) {
  __shared__ float tile[64][129];
  __shared__ float sinv[64];
  int p0 = blockIdx.x * 64;
  int t = threadIdx.x;
  if (t < 64) {
    float cv = cnt[p0 + t];
    sinv[t] = 1.0f / (cv == 0.0f ? 1.0f : cv);
  }
  for (int u = t; u < 64 * 128; u += 256) {
    int pp = u >> 7, c = u & 127;
    tile[pp][c] = accP[(size_t)(p0 + pp) * C1N + c];
  }
  __syncthreads();
  for (int u = t; u < 64 * 128; u += 256) {
    int pp = u & 63, c = u >> 6;
    int g = c * 40000 + p0 + pp;
    out[g] = a[g] + tile[pp][c] * sinv[pp];
  }
}

extern "C" void kernel_launch(void* const* d_in, const int* in_sizes, int n_in,
                              void* d_out, int out_size, void* d_ws, size_t ws_size,
                              hipStream_t stream) {
  const float* list_a = (const float*)d_in[0];
  const float* list_b = (const float*)d_in[1];
  const float* fov   = (const float*)d_in[2];
  const float* Wq    = (const float*)d_in[5];
  const float* bq    = (const float*)d_in[6];
  const float* Wk    = (const float*)d_in[7];
  const float* bk    = (const float*)d_in[8];
  const float* Wv    = (const float*)d_in[9];
  const float* bv    = (const float*)d_in[10];
  const float* inw   = (const float*)d_in[11];
  const float* inb   = (const float*)d_in[12];
  const float* outw  = (const float*)d_in[13];
  const float* outb  = (const float*)d_in[14];
  float* out = (float*)d_out;
  float* ws = (float*)d_ws;

  // Layout (float units):
  // beff 512 | Wb 32768 | P2 9,216,000 (aT overlay; later accP p-major f32)
  // | qb 4,620,288 (UNUSED now — q fused into attn7) | kb 2,949,120
  // | vT 2,949,120 | P0 4,620,288 (a_seq -> o in place, bf16)
  // | P1 2,310,144 (b_seq bf16) | cnt 40,000.
  // accP (5,120,000 f32) lives in P2: aT dead after bilinear2; gemm_os reads
  // A=P0 while atomically writing accP (no alias). kb/vT pad keys keep benign
  // poison across samples (vT pads feed PV MFMA: NaN-reinterp hazard).
  float* beff = ws;
  __hip_bfloat16* Wb = (__hip_bfloat16*)(ws + 512);
  float* P2 = ws + 512 + 32768;
  float* qb_f = P2 + 9216000;
  float* kb_f = qb_f + 4620288;
  float* vT_f = kb_f + 2949120;
  float* P0_f = vT_f + 2949120;
  float* P1_f = P0_f + 4620288;
  float* cnt  = P1_f + 2310144;

  unsigned short* kb = (unsigned short*)kb_f;
  unsigned short* vT = (unsigned short*)vT_f;
  __hip_bfloat16* P0 = (__hip_bfloat16*)P0_f;
  __hip_bfloat16* P1 = (__hip_bfloat16*)P1_f;
  __hip_bfloat16* aT = (__hip_bfloat16*)P2;   // dead after bilinear2
  float* accP = P2;                            // reuses P2 after aT is dead

  weff_k<<<dim3(128, 4), 128, 0, stream>>>(Wq, Wk, Wv, bq, bk, bv, inw, inb, outw, outb, Wb, beff);

  for (int n = 0; n < 2; ++n) {
    const float* a_n = list_a + (size_t)n * C1N * HA * WA;
    const float* b_n = list_b + (size_t)n * C1N * HBB * WBB;
    float* out_n = out + (size_t)n * C1N * HA * WA;

    (void)hipMemsetAsync(cnt, 0, (size_t)HA * WA * sizeof(float), stream);

    transA_k<<<dim3(1250, 4), 256, 0, stream>>>(a_n, aT);
    bilinear2_k<<<dim3(GW, 10), 256, 0, stream>>>(aT, fov, n, P0);
    // aT dead now; zero accP (same P2 region) before the fused scatter.
    (void)hipMemsetAsync(accP, 0, (size_t)HA * WA * C1N * sizeof(float), stream);
    transpose_k<<<dim3(12, 4, 100), 256, 0, stream>>>(b_n, P1);
    gemm_kv_k<<<dim3(563, 2), 256, 0, stream>>>((const unsigned short*)P1,
                                                (const unsigned short*)Wb, beff, kb, vT);
    attn7_k<<<2520, 512, 0, stream>>>((unsigned short*)P0, kb, vT,
                                      (const unsigned short*)Wb, beff);   // q fused; o -> P0
    gemm_os_k<<<1125, 256, 0, stream>>>((const unsigned short*)P0,
                                        (const unsigned short*)Wb, beff, fov, n,
                                        accP, cnt);                        // scatter fused
    finalize2_k<<<625, 256, 0, stream>>>(a_n, accP, cnt, out_n);
  }
}

// Round 10
// 494.543 us; speedup vs baseline: 1.8008x; 1.0235x over previous
//
#include <hip/hip_runtime.h>
#include <hip/hip_bf16.h>
#include <math.h>

#define C1N 128
#define HA 200
#define WA 200
#define HBB 100
#define WBB 360
#define GH 200
#define GW 360
#define NHD 8
#define HDD 16

typedef __attribute__((ext_vector_type(8))) short short8;
typedef __attribute__((ext_vector_type(4))) float f32x4;
typedef __attribute__((ext_vector_type(16))) float f32x16;

__device__ __forceinline__ float bf2f(unsigned short u) {
  union { unsigned int i; float f; } c; c.i = ((unsigned int)u) << 16; return c.f;
}
__device__ __forceinline__ unsigned short f2bf(float f) {
  __hip_bfloat16 h = __float2bfloat16(f);
  unsigned short u;
  __builtin_memcpy(&u, &h, sizeof(u));
  return u;
}

// ---- coordinate pipeline: must match numpy f32 op-for-op. ----
__device__ __forceinline__ void polar_xy(float fov, int i, int j, float& x, float& y) {
#pragma clang fp contract(off)
  float t = (float)j / 359.0f;
  float angle = -fov / 2.0f + fov * t;
  float ca = (float)cos((double)angle);
  float sa = (float)sin((double)angle);
  float rmax = fminf(100.0f / fabsf(ca), 100.0f / fabsf(sa));
  float r = ((float)i / 199.0f) * rmax;
  float xv = 100.0f + r * ca;
  float yv = 100.0f - r * sa;
  x = fminf(fmaxf(xv, 0.0f), 199.0f);
  y = fminf(fmaxf(yv, 0.0f), 199.0f);
}

// Fused weights in bf16: Wb[w<3] = (in_proj_w[w] @ {Wq,Wk,Wv}) ; Wb[3] = out_w.
__global__ void weff_k(const float* __restrict__ Wq, const float* __restrict__ Wk,
                       const float* __restrict__ Wv, const float* __restrict__ bq,
                       const float* __restrict__ bk, const float* __restrict__ bv,
                       const float* __restrict__ inw, const float* __restrict__ inb,
                       const float* __restrict__ outw, const float* __restrict__ outb,
                       __hip_bfloat16* __restrict__ Wb, float* __restrict__ beff) {
  int which = blockIdx.y;
  int o = blockIdx.x;
  int kcol = threadIdx.x;
  if (which == 3) {
    Wb[3 * 16384 + o * 128 + kcol] = __float2bfloat16(outw[o * 128 + kcol]);
    if (kcol == 0) beff[384 + o] = outb[o];
    return;
  }
  const float* Wx = (which == 0) ? Wq : ((which == 1) ? Wk : Wv);
  const float* bx = (which == 0) ? bq : ((which == 1) ? bk : bv);
  const float* wrow = inw + (which * 128 + o) * 128;
  float acc = 0.0f;
  for (int m = 0; m < 128; ++m) acc += wrow[m] * Wx[m * 128 + kcol];
  Wb[which * 16384 + o * 128 + kcol] = __float2bfloat16(acc);
  if (kcol == 0) {
    float bacc = inb[which * 128 + o];
    for (int m = 0; m < 128; ++m) bacc += wrow[m] * bx[m];
    beff[which * 128 + o] = bacc;
  }
}

// a (128,200,200) f32 -> aT[(y*200+x)*128 + c] bf16. LDS 32x32 tiles.
__global__ __launch_bounds__(256) void transA_k(const float* __restrict__ a,
                                                __hip_bfloat16* __restrict__ aT) {
  __shared__ float tile[32][33];
  int p0 = blockIdx.x * 32, c0 = blockIdx.y * 32;
  int tp = threadIdx.x & 31, tr = threadIdx.x >> 5;
  for (int cc = tr; cc < 32; cc += 8)
    tile[cc][tp] = a[(size_t)(c0 + cc) * 40000 + p0 + tp];
  __syncthreads();
  for (int pp = tr; pp < 32; pp += 8)
    aT[(size_t)(p0 + pp) * C1N + c0 + tp] = __float2bfloat16(tile[tp][pp]);
}

// Coalesced bilinear from aT (bf16 p-major).
__global__ __launch_bounds__(256) void bilinear2_k(const __hip_bfloat16* __restrict__ aT,
                                                   const float* __restrict__ fovp, int n,
                                                   __hip_bfloat16* __restrict__ aseq) {
  __shared__ float sw[20][4];
  __shared__ int sp[20][4];
  int j = blockIdx.x;
  int i_base = blockIdx.y * 20;
  int t = threadIdx.x;
  if (t < 20) {
    float x, y;
    polar_xy(fovp[n], i_base + t, j, x, y);
    float x0f = floorf(x), y0f = floorf(y);
    float wx = x - x0f, wy = y - y0f;
    int x0 = max(0, min(199, (int)x0f));
    int x1 = min(x0 + 1, 199);
    int y0 = max(0, min(199, (int)y0f));
    int y1 = min(y0 + 1, 199);
    sp[t][0] = y0 * 200 + x0; sp[t][1] = y0 * 200 + x1;
    sp[t][2] = y1 * 200 + x0; sp[t][3] = y1 * 200 + x1;
    sw[t][0] = (1.0f - wx) * (1.0f - wy); sw[t][1] = wx * (1.0f - wy);
    sw[t][2] = (1.0f - wx) * wy;          sw[t][3] = wx * wy;
  }
  __syncthreads();
  int lane = t & 63, wv = t >> 6;
  for (int ii = wv; ii < 20; ii += 4) {
    int i = i_base + ii;
    float w00 = sw[ii][0], w01 = sw[ii][1], w10 = sw[ii][2], w11 = sw[ii][3];
    ushort2 u00 = ((const ushort2*)(aT + (size_t)sp[ii][0] * C1N))[lane];
    ushort2 u01 = ((const ushort2*)(aT + (size_t)sp[ii][1] * C1N))[lane];
    ushort2 u10 = ((const ushort2*)(aT + (size_t)sp[ii][2] * C1N))[lane];
    ushort2 u11 = ((const ushort2*)(aT + (size_t)sp[ii][3] * C1N))[lane];
    float v0 = w00 * bf2f(u00.x) + w01 * bf2f(u01.x) + w10 * bf2f(u10.x) + w11 * bf2f(u11.x);
    float v1 = w00 * bf2f(u00.y) + w01 * bf2f(u01.y) + w10 * bf2f(u10.y) + w11 * bf2f(u11.y);
    ushort2 outv; outv.x = f2bf(v0); outv.y = f2bf(v1);
    ((ushort2*)(aseq + (size_t)(j * GH + i) * C1N))[lane] = outv;
  }
}

// b (128,100,360) -> bs[(j*100+kk)*128 + c] (bf16)
__global__ __launch_bounds__(256) void transpose_k(const float* __restrict__ b,
                                                   __hip_bfloat16* __restrict__ bs) {
  __shared__ float tile[32][33];
  int kk = blockIdx.z;
  int j0 = blockIdx.x * 32, c0 = blockIdx.y * 32;
  int tj = threadIdx.x & 31;
  int tr = threadIdx.x >> 5;
  for (int cc = tr; cc < 32; cc += 8) {
    int gj = j0 + tj;
    tile[cc][tj] = (gj < WBB) ? b[(c0 + cc) * (HBB * WBB) + kk * WBB + gj] : 0.0f;
  }
  __syncthreads();
  for (int jj = tr; jj < 32; jj += 8) {
    int gj = j0 + jj;
    if (gj < WBB)
      bs[(size_t)(gj * HBB + kk) * C1N + c0 + (threadIdx.x & 31)] =
          __float2bfloat16(tile[threadIdx.x & 31][jj]);
  }
}

// Shared MFMA core: one wave computes 16 rows x 128 cols, K=128.
__device__ __forceinline__ void gemm16_mfma(const unsigned short* __restrict__ A,
                                            const unsigned short* __restrict__ W,
                                            int m_base, f32x4 acc[8]) {
  int lane = threadIdx.x & 63;
  int col = lane & 15, quad = lane >> 4;
#pragma unroll
  for (int nt = 0; nt < 8; ++nt) acc[nt] = (f32x4)0.0f;
#pragma unroll
  for (int s = 0; s < 4; ++s) {
    short8 aF = *(const short8*)&A[(size_t)(m_base + col) * 128 + s * 32 + quad * 8];
#pragma unroll
    for (int nt = 0; nt < 8; ++nt) {
      short8 bF = *(const short8*)&W[(size_t)(nt * 16 + col) * 128 + s * 32 + quad * 8];
      acc[nt] = __builtin_amdgcn_mfma_f32_16x16x32_bf16(aF, bF, acc[nt], 0, 0, 0);
    }
  }
}

// Stage the block's 64x128 bf16 output into LDS (MFMA lane layout -> row-major).
__device__ __forceinline__ void stage_bf16(unsigned short (*tile)[136],
                                           const f32x4 acc[8],
                                           const float* __restrict__ bias) {
  int lane = threadIdx.x & 63, wv = threadIdx.x >> 6;
  int col = lane & 15, quad = lane >> 4;
#pragma unroll
  for (int nt = 0; nt < 8; ++nt) {
    float bb = bias[nt * 16 + col];
#pragma unroll
    for (int r = 0; r < 4; ++r)
      tile[wv * 16 + quad * 4 + r][nt * 16 + col] = f2bf(acc[nt][r] + bb);
  }
  __syncthreads();
}

// k' -> kb [j][key(pad128)][col] and v' -> vT [j][col][key(pad128)], fused.
// Grid (563, 2); M = 36000. Tail A-reads stay inside P1 (36096 rows); poison
// benign. Stores only touch real keys; kb/vT pad keys keep benign poison
// (vT pads feed PV MFMA via P=0 — NaN-reinterp hazard if overwritten).
__global__ __launch_bounds__(256) void gemm_kv_k(const unsigned short* __restrict__ A,
                                                 const unsigned short* __restrict__ Wb,
                                                 const float* __restrict__ beff,
                                                 unsigned short* __restrict__ kb,
                                                 unsigned short* __restrict__ vT) {
  __shared__ unsigned short tile[64][136];
  int which = blockIdx.y;
  int m0 = blockIdx.x * 64;
  f32x4 acc[8];
  gemm16_mfma(A, Wb + (which ? 32768 : 16384), m0 + (threadIdx.x >> 6) * 16, acc);
  stage_bf16(tile, acc, beff + (which ? 256 : 128));
  if (which == 0) {
    for (int u = threadIdx.x; u < 1024; u += 256) {
      int rl = u >> 4, ch = (u & 15) * 8;
      int row = m0 + rl;
      if (row < 36000) {
        int jj = row / 100, key = row - jj * 100;
        *(short8*)&kb[((size_t)jj * 128 + key) * 128 + ch] = *(const short8*)&tile[rl][ch];
      }
    }
  } else {
    for (int u = threadIdx.x; u < 8192; u += 256) {
      int cc = u >> 6, kl = u & 63;
      int row = m0 + kl;
      if (row < 36000) {
        int jj = row / 100, key = row - jj * 100;
        vT[((size_t)jj * 128 + cc) * 128 + key] = tile[kl][cc];
      }
    }
  }
}

// MFMA attention v8 = attn7 with the LDS P-buffer replaced by in-register P
// exchange via v_permlane32_swap (HipKittens T12). After swapped QK^T, lane
// (q=col, half) holds P[key] for keys {0-3,8-11,...}+4*half (mod 32) per
// 32-block; the PV A-fragment aP[i] = P[16ks+8*half+i][col] needs own pack
// u[nt][2(ks&1)+half] plus the partner lane's complementary pack — ONE
// permlane32_swap of (u[nt][2p].w, u[nt][2p+1].w) yields BOTH needed words:
//   res0 = {own lo-pack | partner lo-pack}, res1 = {partner hi | own hi}.
// Kills Ps (61440 B LDS -> 0), its writes/reads, and their bank conflicts.
// LDS now 8704 B -> occupancy VGPR-bound (was 2 blocks/CU, 40%).
// Phase 0 (q-projection fused) and all layouts unchanged from attn7.
__global__ __launch_bounds__(512) void attn8_k(unsigned short* __restrict__ aseq_o,
                                               const unsigned short* __restrict__ kb,
                                               const unsigned short* __restrict__ vT,
                                               const unsigned short* __restrict__ Wb,
                                               const float* __restrict__ beff) {
  __shared__ unsigned short qos[32][136];    // 8704 B: qTile, then Osh
  int d = blockIdx.x;
  int xcd = d & 7, idx = d >> 3;            // idx in [0,315)
  int j = xcd * 45 + idx % 45;
  int mt = idx / 45;
  int h = threadIdx.x >> 6;
  int lane = threadIdx.x & 63;
  int col = lane & 31, half = lane >> 5;
  int col16 = lane & 15, quad = lane >> 4;

  // ---- phase 0: fused q-projection into qos (as qTile) ----
  {
    int rs = h & 1;                  // row strip: rows rs*16 .. +16
    int ng = h >> 1;                 // col group: nt = ng*2 + {0,1}
    int m_base = j * 200 + mt * 32 + rs * 16;
    f32x4 qacc[2];
    qacc[0] = (f32x4)0.0f; qacc[1] = (f32x4)0.0f;
#pragma unroll
    for (int s = 0; s < 4; ++s) {
      short8 aF = *(const short8*)&aseq_o[(size_t)(m_base + col16) * 128 + s * 32 + quad * 8];
#pragma unroll
      for (int i = 0; i < 2; ++i) {
        int nt = ng * 2 + i;
        short8 bF = *(const short8*)&Wb[(size_t)(nt * 16 + col16) * 128 + s * 32 + quad * 8];
        qacc[i] = __builtin_amdgcn_mfma_f32_16x16x32_bf16(aF, bF, qacc[i], 0, 0, 0);
      }
    }
#pragma unroll
    for (int i = 0; i < 2; ++i) {
      int nt = ng * 2 + i;
      float bb = beff[nt * 16 + col16];
#pragma unroll
      for (int r = 0; r < 4; ++r)
        qos[rs * 16 + quad * 4 + r][nt * 16 + col16] = f2bf(qacc[i][r] + bb);
    }
  }
  __syncthreads();

  // ---- S' = K Q^T (A: key rows, B: q rows; K=16=head_dim) ----
  short8 qF = *(const short8*)&qos[col][h * 16 + half * 8];
  f32x16 S[4];
#pragma unroll
  for (int nt = 0; nt < 4; ++nt) {
    short8 kF = *(const short8*)&kb[((size_t)j * 128 + nt * 32 + col) * 128 + h * 16 + half * 8];
    S[nt] = __builtin_amdgcn_mfma_f32_32x32x16_bf16(kF, qF, (f32x16)0.0f, 0, 0, 0);
  }

  // ---- exp + key mask (compile-time) + row sum over lane pair ----
  float rsum = 0.0f;
#pragma unroll
  for (int nt = 0; nt < 3; ++nt)
#pragma unroll
    for (int r = 0; r < 16; ++r) {
      float e = __expf(S[nt][r] * 0.25f);
      S[nt][r] = e; rsum += e;
    }
#pragma unroll
  for (int r = 0; r < 16; ++r) {
    float e = (half == 0 && r < 4) ? __expf(S[3][r] * 0.25f) : 0.0f;
    S[3][r] = e; rsum += e;
  }
  rsum += __shfl_xor(rsum, 32, 64);
  float inv = __fdividef(1.0f, rsum);

  // ---- PV with in-register P: per nt, pack then 2 MFMA (ks=2nt, 2nt+1) ----
  short8 ones;
#pragma unroll
  for (int i = 0; i < 8; ++i) ones[i] = (short)0x3F80;
  const unsigned short* vrow = &vT[((size_t)j * 128 + h * 16 + col16) * 128];
  f32x16 O = (f32x16)0.0f;
#pragma unroll
  for (int nt = 0; nt < 4; ++nt) {
    // pack normalized P[nt] into uint pairs u[g] = keys 32nt + 8g + 4half + {0..3}
    unsigned int ux[4], uy[4];
#pragma unroll
    for (int g = 0; g < 4; ++g) {
      if (nt == 3 && g >= 2) { ux[g] = 0; uy[g] = 0; continue; }
      float e0 = S[nt][4 * g + 0] * inv, e1 = S[nt][4 * g + 1] * inv;
      float e2 = S[nt][4 * g + 2] * inv, e3 = S[nt][4 * g + 3] * inv;
      asm("v_cvt_pk_bf16_f32 %0, %1, %2" : "=v"(ux[g]) : "v"(e0), "v"(e1));
      asm("v_cvt_pk_bf16_f32 %0, %1, %2" : "=v"(uy[g]) : "v"(e2), "v"(e3));
    }
#pragma unroll
    for (int p = 0; p < 2; ++p) {
      int ks = 2 * nt + p;
      if (ks >= 7) continue;  // keys 112..127 never used
      // exchange: res0 = {own g=2p lo | partner}, res1 = {partner | own g=2p+1}
      unsigned int ax = ux[2 * p], bx = ux[2 * p + 1];
      asm("v_permlane32_swap_b32 %0, %1" : "+v"(ax), "+v"(bx));
      unsigned int ay = uy[2 * p], by = uy[2 * p + 1];
      asm("v_permlane32_swap_b32 %0, %1" : "+v"(ay), "+v"(by));
      union { unsigned int u4[4]; short8 s8; } cvt;
      cvt.u4[0] = ax; cvt.u4[1] = ay; cvt.u4[2] = bx; cvt.u4[3] = by;
      short8 bV = (col < 16) ? *(const short8*)&vrow[ks * 16 + half * 8] : ones;
      O = __builtin_amdgcn_mfma_f32_32x32x16_bf16(cvt.s8, bV, O, 0, 0, 0);
    }
  }

  // ---- stage O into qos (qTile dead after qF reads) and store ----
  __syncthreads();
#pragma unroll
  for (int r = 0; r < 16; ++r) {
    int row = (r & 3) + 8 * (r >> 2) + 4 * half;
    if (col < 16) qos[row][h * 16 + col] = f2bf(O[r]);
  }
  __syncthreads();
  int rl = threadIdx.x >> 4, ch = (threadIdx.x & 15) * 8;
  int qr = mt * 32 + rl;
  if (qr < 200)
    *(short8*)&aseq_o[(size_t)(j * 200 + qr) * 128 + ch] = *(const short8*)&qos[rl][ch];
}

// zero accP (5,120,000 f) + cnt (40,000 f) in one pass — replaces two
// hipMemsetAsync (rocprof showed fillBufferAligned at 41us / 268MB written).
__global__ __launch_bounds__(256) void zero_k(float* __restrict__ accP,
                                              float* __restrict__ cnt) {
  int t = blockIdx.x * 256 + threadIdx.x;
  for (int u = t; u < 1280000; u += 524288) ((f32x4*)accP)[u] = (f32x4)0.0f;
  if (t < 10000) ((f32x4*)cnt)[t] = (f32x4)0.0f;
}

// Fused out-projection + scatter: C = o @ Wout^T + b into an LDS f32 tile,
// pixel indices per row (each row evaluated exactly once), cnt bumped, then a
// run-merged atomicAdd walk over the LDS tile into accP (p-major).
// M = 72000 = 1125*64 (no tail). accP lives in P2 (aT dead; never aliases A).
__global__ __launch_bounds__(256) void gemm_os_k(const unsigned short* __restrict__ A,
                                                 const unsigned short* __restrict__ Wb,
                                                 const float* __restrict__ beff,
                                                 const float* __restrict__ fovp, int n,
                                                 float* __restrict__ accP,
                                                 float* __restrict__ cnt) {
  __shared__ float tile[64][132];
  __shared__ int sidx[64];
  int m0 = blockIdx.x * 64;
  int t = threadIdx.x;
  f32x4 acc[8];
  gemm16_mfma(A, Wb + 49152, m0 + (t >> 6) * 16, acc);
  if (t < 64) {
    int m = m0 + t;
    int j = m / 200, i = m - j * 200;
    float x, y;
    polar_xy(fovp[n], i, j, x, y);
    int xi = (int)rintf(x); xi = max(0, min(199, xi));
    int yi = (int)rintf(y); yi = max(0, min(199, yi));
    sidx[t] = yi * 200 + xi;
    atomicAdd(&cnt[yi * 200 + xi], 1.0f);
  }
  {
    int lane = t & 63, wv = t >> 6;
    int col = lane & 15, quad = lane >> 4;
#pragma unroll
    for (int nt = 0; nt < 8; ++nt) {
      float bb = beff[384 + nt * 16 + col];
#pragma unroll
      for (int r = 0; r < 4; ++r)
        tile[wv * 16 + quad * 4 + r][nt * 16 + col] = acc[nt][r] + bb;
    }
  }
  __syncthreads();
  int c = t & 127, half = t >> 7;
  int r0 = half * 32;
  int cur = sidx[r0];
  float sum = 0.0f;
#pragma unroll 4
  for (int r = r0; r < r0 + 32; ++r) {
    float v = tile[r][c];
    int idx = sidx[r];
    if (idx != cur) {
      atomicAdd(&accP[(size_t)cur * C1N + c], sum);
      cur = idx;
      sum = v;
    } else {
      sum += v;
    }
  }
  atomicAdd(&accP[(size_t)cur * C1N + c], sum);
}

// out = a + accP/cnt (LDS transpose, coalesced both sides).
__global__ __launch_bounds__(256) void finalize2_k(const float* __restrict__ a,
                                                   const float* __restrict__ accP,
                                                   const float* __restrict__ cnt,
                                                   float* __restrict__ out) {
  __shared__ float tile[64][129];
  __shared__ float sinv[64];
  int p0 = blockIdx.x * 64;
  int t = threadIdx.x;
  if (t < 64) {
    float cv = cnt[p0 + t];
    sinv[t] = 1.0f / (cv == 0.0f ? 1.0f : cv);
  }
  for (int u = t; u < 64 * 128; u += 256) {
    int pp = u >> 7, c = u & 127;
    tile[pp][c] = accP[(size_t)(p0 + pp) * C1N + c];
  }
  __syncthreads();
  for (int u = t; u < 64 * 128; u += 256) {
    int pp = u & 63, c = u >> 6;
    int g = c * 40000 + p0 + pp;
    out[g] = a[g] + tile[pp][c] * sinv[pp];
  }
}

extern "C" void kernel_launch(void* const* d_in, const int* in_sizes, int n_in,
                              void* d_out, int out_size, void* d_ws, size_t ws_size,
                              hipStream_t stream) {
  const float* list_a = (const float*)d_in[0];
  const float* list_b = (const float*)d_in[1];
  const float* fov   = (const float*)d_in[2];
  const float* Wq    = (const float*)d_in[5];
  const float* bq    = (const float*)d_in[6];
  const float* Wk    = (const float*)d_in[7];
  const float* bk    = (const float*)d_in[8];
  const float* Wv    = (const float*)d_in[9];
  const float* bv    = (const float*)d_in[10];
  const float* inw   = (const float*)d_in[11];
  const float* inb   = (const float*)d_in[12];
  const float* outw  = (const float*)d_in[13];
  const float* outb  = (const float*)d_in[14];
  float* out = (float*)d_out;
  float* ws = (float*)d_ws;

  // Layout (float units):
  // beff 512 | Wb 32768 | P2 9,216,000 (aT overlay; later accP p-major f32)
  // | qb 4,620,288 (unused — q fused into attn8) | kb 2,949,120
  // | vT 2,949,120 | P0 4,620,288 (a_seq -> o in place, bf16)
  // | P1 2,310,144 (b_seq bf16) | cnt 40,000.
  // accP (5,120,000 f32) lives in P2: aT dead after bilinear2; gemm_os reads
  // A=P0 while atomically writing accP (no alias). kb/vT pad keys keep benign
  // poison across samples (vT pads feed PV MFMA: NaN-reinterp hazard).
  float* beff = ws;
  __hip_bfloat16* Wb = (__hip_bfloat16*)(ws + 512);
  float* P2 = ws + 512 + 32768;
  float* qb_f = P2 + 9216000;
  float* kb_f = qb_f + 4620288;
  float* vT_f = kb_f + 2949120;
  float* P0_f = vT_f + 2949120;
  float* P1_f = P0_f + 4620288;
  float* cnt  = P1_f + 2310144;

  unsigned short* kb = (unsigned short*)kb_f;
  unsigned short* vT = (unsigned short*)vT_f;
  __hip_bfloat16* P0 = (__hip_bfloat16*)P0_f;
  __hip_bfloat16* P1 = (__hip_bfloat16*)P1_f;
  __hip_bfloat16* aT = (__hip_bfloat16*)P2;   // dead after bilinear2
  float* accP = P2;                            // reuses P2 after aT is dead

  weff_k<<<dim3(128, 4), 128, 0, stream>>>(Wq, Wk, Wv, bq, bk, bv, inw, inb, outw, outb, Wb, beff);

  for (int n = 0; n < 2; ++n) {
    const float* a_n = list_a + (size_t)n * C1N * HA * WA;
    const float* b_n = list_b + (size_t)n * C1N * HBB * WBB;
    float* out_n = out + (size_t)n * C1N * HA * WA;

    transA_k<<<dim3(1250, 4), 256, 0, stream>>>(a_n, aT);
    bilinear2_k<<<dim3(GW, 10), 256, 0, stream>>>(aT, fov, n, P0);
    // aT dead now; zero accP (same P2 region) + cnt with one kernel.
    zero_k<<<2048, 256, 0, stream>>>(accP, cnt);
    transpose_k<<<dim3(12, 4, 100), 256, 0, stream>>>(b_n, P1);
    gemm_kv_k<<<dim3(563, 2), 256, 0, stream>>>((const unsigned short*)P1,
                                                (const unsigned short*)Wb, beff, kb, vT);
    attn8_k<<<2520, 512, 0, stream>>>((unsigned short*)P0, kb, vT,
                                      (const unsigned short*)Wb, beff);   // q fused; o -> P0
    gemm_os_k<<<1125, 256, 0, stream>>>((const unsigned short*)P0,
                                        (const unsigned short*)Wb, beff, fov, n,
                                        accP, cnt);                        // scatter fused
    finalize2_k<<<625, 256, 0, stream>>>(a_n, accP, cnt, out_n);
  }
}

// Round 11
// 466.744 us; speedup vs baseline: 1.9081x; 1.0596x over previous
//
#include <hip/hip_runtime.h>
#include <hip/hip_bf16.h>
#include <math.h>

#define C1N 128
#define HA 200
#define WA 200
#define HBB 100
#define WBB 360
#define GH 200
#define GW 360
#define NHD 8
#define HDD 16

// per-sample strides (shorts unless noted)
#define P0S 9240576     // P0_n stride (4,620,288 floats)
#define KVS 11796480    // kb_n / vT_n stride (5,898,240 floats)
#define P1S 4620288     // P1_n stride (2,310,144 floats)
#define ATS 5120000     // aT_n stride (2,560,000 floats)
#define ACCS 5120000    // accP_n stride (floats)
#define CNTS 40000      // cnt_n stride (floats)

typedef __attribute__((ext_vector_type(8))) short short8;
typedef __attribute__((ext_vector_type(4))) float f32x4;
typedef __attribute__((ext_vector_type(16))) float f32x16;

__device__ __forceinline__ float bf2f(unsigned short u) {
  union { unsigned int i; float f; } c; c.i = ((unsigned int)u) << 16; return c.f;
}
__device__ __forceinline__ unsigned short f2bf(float f) {
  __hip_bfloat16 h = __float2bfloat16(f);
  unsigned short u;
  __builtin_memcpy(&u, &h, sizeof(u));
  return u;
}

// ---- coordinate pipeline: must match numpy f32 op-for-op. ----
__device__ __forceinline__ void polar_xy(float fov, int i, int j, float& x, float& y) {
#pragma clang fp contract(off)
  float t = (float)j / 359.0f;
  float angle = -fov / 2.0f + fov * t;
  float ca = (float)cos((double)angle);
  float sa = (float)sin((double)angle);
  float rmax = fminf(100.0f / fabsf(ca), 100.0f / fabsf(sa));
  float r = ((float)i / 199.0f) * rmax;
  float xv = 100.0f + r * ca;
  float yv = 100.0f - r * sa;
  x = fminf(fmaxf(xv, 0.0f), 199.0f);
  y = fminf(fmaxf(yv, 0.0f), 199.0f);
}

// Fused weights in bf16: Wb[w<3] = (in_proj_w[w] @ {Wq,Wk,Wv}) ; Wb[3] = out_w.
__global__ void weff_k(const float* __restrict__ Wq, const float* __restrict__ Wk,
                       const float* __restrict__ Wv, const float* __restrict__ bq,
                       const float* __restrict__ bk, const float* __restrict__ bv,
                       const float* __restrict__ inw, const float* __restrict__ inb,
                       const float* __restrict__ outw, const float* __restrict__ outb,
                       __hip_bfloat16* __restrict__ Wb, float* __restrict__ beff) {
  int which = blockIdx.y;
  int o = blockIdx.x;
  int kcol = threadIdx.x;
  if (which == 3) {
    Wb[3 * 16384 + o * 128 + kcol] = __float2bfloat16(outw[o * 128 + kcol]);
    if (kcol == 0) beff[384 + o] = outb[o];
    return;
  }
  const float* Wx = (which == 0) ? Wq : ((which == 1) ? Wk : Wv);
  const float* bx = (which == 0) ? bq : ((which == 1) ? bk : bv);
  const float* wrow = inw + (which * 128 + o) * 128;
  float acc = 0.0f;
  for (int m = 0; m < 128; ++m) acc += wrow[m] * Wx[m * 128 + kcol];
  Wb[which * 16384 + o * 128 + kcol] = __float2bfloat16(acc);
  if (kcol == 0) {
    float bacc = inb[which * 128 + o];
    for (int m = 0; m < 128; ++m) bacc += wrow[m] * bx[m];
    beff[which * 128 + o] = bacc;
  }
}

// a (128,200,200) f32 -> aT[(y*200+x)*128 + c] bf16. Both samples: z = n.
__global__ __launch_bounds__(256) void transA_k(const float* __restrict__ a,
                                                __hip_bfloat16* __restrict__ aT) {
  __shared__ float tile[32][33];
  int n = blockIdx.z;
  const float* an = a + (size_t)n * 5120000;
  __hip_bfloat16* aTn = aT + (size_t)n * ATS;
  int p0 = blockIdx.x * 32, c0 = blockIdx.y * 32;
  int tp = threadIdx.x & 31, tr = threadIdx.x >> 5;
  for (int cc = tr; cc < 32; cc += 8)
    tile[cc][tp] = an[(size_t)(c0 + cc) * 40000 + p0 + tp];
  __syncthreads();
  for (int pp = tr; pp < 32; pp += 8)
    aTn[(size_t)(p0 + pp) * C1N + c0 + tp] = __float2bfloat16(tile[tp][pp]);
}

// Coalesced bilinear from aT (bf16 p-major). Both samples: z = n.
__global__ __launch_bounds__(256) void bilinear2_k(const __hip_bfloat16* __restrict__ aT,
                                                   const float* __restrict__ fovp,
                                                   __hip_bfloat16* __restrict__ aseq) {
  __shared__ float sw[20][4];
  __shared__ int sp[20][4];
  int n = blockIdx.z;
  const __hip_bfloat16* aTn = aT + (size_t)n * ATS;
  __hip_bfloat16* aseqn = aseq + (size_t)n * P0S;
  int j = blockIdx.x;
  int i_base = blockIdx.y * 20;
  int t = threadIdx.x;
  if (t < 20) {
    float x, y;
    polar_xy(fovp[n], i_base + t, j, x, y);
    float x0f = floorf(x), y0f = floorf(y);
    float wx = x - x0f, wy = y - y0f;
    int x0 = max(0, min(199, (int)x0f));
    int x1 = min(x0 + 1, 199);
    int y0 = max(0, min(199, (int)y0f));
    int y1 = min(y0 + 1, 199);
    sp[t][0] = y0 * 200 + x0; sp[t][1] = y0 * 200 + x1;
    sp[t][2] = y1 * 200 + x0; sp[t][3] = y1 * 200 + x1;
    sw[t][0] = (1.0f - wx) * (1.0f - wy); sw[t][1] = wx * (1.0f - wy);
    sw[t][2] = (1.0f - wx) * wy;          sw[t][3] = wx * wy;
  }
  __syncthreads();
  int lane = t & 63, wv = t >> 6;
  for (int ii = wv; ii < 20; ii += 4) {
    int i = i_base + ii;
    float w00 = sw[ii][0], w01 = sw[ii][1], w10 = sw[ii][2], w11 = sw[ii][3];
    ushort2 u00 = ((const ushort2*)(aTn + (size_t)sp[ii][0] * C1N))[lane];
    ushort2 u01 = ((const ushort2*)(aTn + (size_t)sp[ii][1] * C1N))[lane];
    ushort2 u10 = ((const ushort2*)(aTn + (size_t)sp[ii][2] * C1N))[lane];
    ushort2 u11 = ((const ushort2*)(aTn + (size_t)sp[ii][3] * C1N))[lane];
    float v0 = w00 * bf2f(u00.x) + w01 * bf2f(u01.x) + w10 * bf2f(u10.x) + w11 * bf2f(u11.x);
    float v1 = w00 * bf2f(u00.y) + w01 * bf2f(u01.y) + w10 * bf2f(u10.y) + w11 * bf2f(u11.y);
    ushort2 outv; outv.x = f2bf(v0); outv.y = f2bf(v1);
    ((ushort2*)(aseqn + (size_t)(j * GH + i) * C1N))[lane] = outv;
  }
}

// b (128,100,360) -> bs[(j*100+kk)*128 + c] (bf16). n folded into x.
__global__ __launch_bounds__(256) void transpose_k(const float* __restrict__ b,
                                                   __hip_bfloat16* __restrict__ bs) {
  __shared__ float tile[32][33];
  int bx = blockIdx.x;
  int n = bx / 12;
  const float* bn = b + (size_t)n * 4608000;
  __hip_bfloat16* bsn = bs + (size_t)n * P1S;
  int kk = blockIdx.z;
  int j0 = (bx % 12) * 32, c0 = blockIdx.y * 32;
  int tj = threadIdx.x & 31;
  int tr = threadIdx.x >> 5;
  for (int cc = tr; cc < 32; cc += 8) {
    int gj = j0 + tj;
    tile[cc][tj] = (gj < WBB) ? bn[(c0 + cc) * (HBB * WBB) + kk * WBB + gj] : 0.0f;
  }
  __syncthreads();
  for (int jj = tr; jj < 32; jj += 8) {
    int gj = j0 + jj;
    if (gj < WBB)
      bsn[(size_t)(gj * HBB + kk) * C1N + c0 + (threadIdx.x & 31)] =
          __float2bfloat16(tile[threadIdx.x & 31][jj]);
  }
}

// Shared MFMA core: one wave computes 16 rows x 128 cols, K=128.
__device__ __forceinline__ void gemm16_mfma(const unsigned short* __restrict__ A,
                                            const unsigned short* __restrict__ W,
                                            int m_base, f32x4 acc[8]) {
  int lane = threadIdx.x & 63;
  int col = lane & 15, quad = lane >> 4;
#pragma unroll
  for (int nt = 0; nt < 8; ++nt) acc[nt] = (f32x4)0.0f;
#pragma unroll
  for (int s = 0; s < 4; ++s) {
    short8 aF = *(const short8*)&A[(size_t)(m_base + col) * 128 + s * 32 + quad * 8];
#pragma unroll
    for (int nt = 0; nt < 8; ++nt) {
      short8 bF = *(const short8*)&W[(size_t)(nt * 16 + col) * 128 + s * 32 + quad * 8];
      acc[nt] = __builtin_amdgcn_mfma_f32_16x16x32_bf16(aF, bF, acc[nt], 0, 0, 0);
    }
  }
}

// Stage the block's 64x128 bf16 output into LDS (MFMA lane layout -> row-major).
__device__ __forceinline__ void stage_bf16(unsigned short (*tile)[136],
                                           const f32x4 acc[8],
                                           const float* __restrict__ bias) {
  int lane = threadIdx.x & 63, wv = threadIdx.x >> 6;
  int col = lane & 15, quad = lane >> 4;
#pragma unroll
  for (int nt = 0; nt < 8; ++nt) {
    float bb = bias[nt * 16 + col];
#pragma unroll
    for (int r = 0; r < 4; ++r)
      tile[wv * 16 + quad * 4 + r][nt * 16 + col] = f2bf(acc[nt][r] + bb);
  }
  __syncthreads();
}

// k' -> kb [j][key(pad128)][col] and v' -> vT [j][col][key(pad128)], fused.
// Grid (563, 2, 2): y = which, z = n. M = 36000; tail reads stay in P1_n.
// Pads: kb pads only feed discarded S outputs; vT pads are MASKED IN-REGISTER
// at PV (attn9) -> no memory-hygiene invariant remains.
__global__ __launch_bounds__(256) void gemm_kv_k(const unsigned short* __restrict__ P1b,
                                                 const unsigned short* __restrict__ Wb,
                                                 const float* __restrict__ beff,
                                                 unsigned short* __restrict__ kbB,
                                                 unsigned short* __restrict__ vTB) {
  __shared__ unsigned short tile[64][136];
  int which = blockIdx.y;
  int n = blockIdx.z;
  const unsigned short* A = P1b + (size_t)n * P1S;
  unsigned short* kb = kbB + (size_t)n * KVS;
  unsigned short* vT = vTB + (size_t)n * KVS;
  int m0 = blockIdx.x * 64;
  f32x4 acc[8];
  gemm16_mfma(A, Wb + (which ? 32768 : 16384), m0 + (threadIdx.x >> 6) * 16, acc);
  stage_bf16(tile, acc, beff + (which ? 256 : 128));
  if (which == 0) {
    for (int u = threadIdx.x; u < 1024; u += 256) {
      int rl = u >> 4, ch = (u & 15) * 8;
      int row = m0 + rl;
      if (row < 36000) {
        int jj = row / 100, key = row - jj * 100;
        *(short8*)&kb[((size_t)jj * 128 + key) * 128 + ch] = *(const short8*)&tile[rl][ch];
      }
    }
  } else {
    for (int u = threadIdx.x; u < 8192; u += 256) {
      int cc = u >> 6, kl = u & 63;
      int row = m0 + kl;
      if (row < 36000) {
        int jj = row / 100, key = row - jj * 100;
        vT[((size_t)jj * 128 + cc) * 128 + key] = tile[kl][cc];
      }
    }
  }
}

// MFMA attention v9 = attn8 (fused q-proj, in-register P via permlane32_swap)
// + both samples (grid (2520, 2), y = n) + IN-REGISTER V-pad masking:
// ks=6 covers keys 96..111; keys 100..111 are pads whose content is now
// arbitrary (accP overlays vT between launches) -> zero those bV elements
// before the MFMA (0 x P=0 = 0; NaN never enters). Kills the poison invariant.
__global__ __launch_bounds__(512) void attn9_k(unsigned short* __restrict__ P0b,
                                               const unsigned short* __restrict__ kbB,
                                               const unsigned short* __restrict__ vTB,
                                               const unsigned short* __restrict__ Wb,
                                               const float* __restrict__ beff) {
  __shared__ unsigned short qos[32][136];    // 8704 B: qTile, then Osh
  int nS = blockIdx.y;
  unsigned short* aseq_o = P0b + (size_t)nS * P0S;
  const unsigned short* kb = kbB + (size_t)nS * KVS;
  const unsigned short* vT = vTB + (size_t)nS * KVS;
  int d = blockIdx.x;
  int xcd = d & 7, idx = d >> 3;            // idx in [0,315)
  int j = xcd * 45 + idx % 45;              // all 7 mt of a j share d%8 -> XCD
  int mt = idx / 45;
  int h = threadIdx.x >> 6;
  int lane = threadIdx.x & 63;
  int col = lane & 31, half = lane >> 5;
  int col16 = lane & 15, quad = lane >> 4;

  // ---- phase 0: fused q-projection into qos (as qTile) ----
  {
    int rs = h & 1;
    int ng = h >> 1;
    int m_base = j * 200 + mt * 32 + rs * 16;
    f32x4 qacc[2];
    qacc[0] = (f32x4)0.0f; qacc[1] = (f32x4)0.0f;
#pragma unroll
    for (int s = 0; s < 4; ++s) {
      short8 aF = *(const short8*)&aseq_o[(size_t)(m_base + col16) * 128 + s * 32 + quad * 8];
#pragma unroll
      for (int i = 0; i < 2; ++i) {
        int nt = ng * 2 + i;
        short8 bF = *(const short8*)&Wb[(size_t)(nt * 16 + col16) * 128 + s * 32 + quad * 8];
        qacc[i] = __builtin_amdgcn_mfma_f32_16x16x32_bf16(aF, bF, qacc[i], 0, 0, 0);
      }
    }
#pragma unroll
    for (int i = 0; i < 2; ++i) {
      int nt = ng * 2 + i;
      float bb = beff[nt * 16 + col16];
#pragma unroll
      for (int r = 0; r < 4; ++r)
        qos[rs * 16 + quad * 4 + r][nt * 16 + col16] = f2bf(qacc[i][r] + bb);
    }
  }
  __syncthreads();

  // ---- S' = K Q^T ----
  short8 qF = *(const short8*)&qos[col][h * 16 + half * 8];
  f32x16 S[4];
#pragma unroll
  for (int nt = 0; nt < 4; ++nt) {
    short8 kF = *(const short8*)&kb[((size_t)j * 128 + nt * 32 + col) * 128 + h * 16 + half * 8];
    S[nt] = __builtin_amdgcn_mfma_f32_32x32x16_bf16(kF, qF, (f32x16)0.0f, 0, 0, 0);
  }

  // ---- exp + key mask + row sum over lane pair ----
  float rsum = 0.0f;
#pragma unroll
  for (int nt = 0; nt < 3; ++nt)
#pragma unroll
    for (int r = 0; r < 16; ++r) {
      float e = __expf(S[nt][r] * 0.25f);
      S[nt][r] = e; rsum += e;
    }
#pragma unroll
  for (int r = 0; r < 16; ++r) {
    float e = (half == 0 && r < 4) ? __expf(S[3][r] * 0.25f) : 0.0f;
    S[3][r] = e; rsum += e;
  }
  rsum += __shfl_xor(rsum, 32, 64);
  float inv = __fdividef(1.0f, rsum);

  // ---- PV with in-register P ----
  short8 ones;
#pragma unroll
  for (int i = 0; i < 8; ++i) ones[i] = (short)0x3F80;
  const unsigned short* vrow = &vT[((size_t)j * 128 + h * 16 + col16) * 128];
  f32x16 O = (f32x16)0.0f;
#pragma unroll
  for (int nt = 0; nt < 4; ++nt) {
    unsigned int ux[4], uy[4];
#pragma unroll
    for (int g = 0; g < 4; ++g) {
      if (nt == 3 && g >= 2) { ux[g] = 0; uy[g] = 0; continue; }
      float e0 = S[nt][4 * g + 0] * inv, e1 = S[nt][4 * g + 1] * inv;
      float e2 = S[nt][4 * g + 2] * inv, e3 = S[nt][4 * g + 3] * inv;
      asm("v_cvt_pk_bf16_f32 %0, %1, %2" : "=v"(ux[g]) : "v"(e0), "v"(e1));
      asm("v_cvt_pk_bf16_f32 %0, %1, %2" : "=v"(uy[g]) : "v"(e2), "v"(e3));
    }
#pragma unroll
    for (int p = 0; p < 2; ++p) {
      int ks = 2 * nt + p;
      if (ks >= 7) continue;
      unsigned int ax = ux[2 * p], bx = ux[2 * p + 1];
      asm("v_permlane32_swap_b32 %0, %1" : "+v"(ax), "+v"(bx));
      unsigned int ay = uy[2 * p], by = uy[2 * p + 1];
      asm("v_permlane32_swap_b32 %0, %1" : "+v"(ay), "+v"(by));
      union { unsigned int u4[4]; short8 s8; } cvt;
      cvt.u4[0] = ax; cvt.u4[1] = ay; cvt.u4[2] = bx; cvt.u4[3] = by;
      short8 bV;
      if (col < 16) {
        bV = *(const short8*)&vrow[ks * 16 + half * 8];
        if (ks == 6) {  // keys 96..111: zero pad keys 100..111 in-register
          if (half) {
#pragma unroll
            for (int e = 0; e < 8; ++e) bV[e] = 0;   // keys 104..111 all pad
          } else {
            bV[4] = 0; bV[5] = 0; bV[6] = 0; bV[7] = 0;  // keys 100..103
          }
        }
      } else {
        bV = ones;
      }
      O = __builtin_amdgcn_mfma_f32_32x32x16_bf16(cvt.s8, bV, O, 0, 0, 0);
    }
  }

  // ---- stage O into qos and store ----
  __syncthreads();
#pragma unroll
  for (int r = 0; r < 16; ++r) {
    int row = (r & 3) + 8 * (r >> 2) + 4 * half;
    if (col < 16) qos[row][h * 16 + col] = f2bf(O[r]);
  }
  __syncthreads();
  int rl = threadIdx.x >> 4, ch = (threadIdx.x & 15) * 8;
  int qr = mt * 32 + rl;
  if (qr < 200)
    *(short8*)&aseq_o[(size_t)(j * 200 + qr) * 128 + ch] = *(const short8*)&qos[rl][ch];
}

// zero the S2 region reused as accP x2 + cnt x2 (10,320,000 floats).
__global__ __launch_bounds__(256) void zero_k(float* __restrict__ p) {
  int t = blockIdx.x * 256 + threadIdx.x;
  for (int u = t; u < 2580000; u += 524288) ((f32x4*)p)[u] = (f32x4)0.0f;
}

// Fused out-projection + scatter, both samples (grid (1125, 2), y = n).
__global__ __launch_bounds__(256) void gemm_os_k(const unsigned short* __restrict__ P0b,
                                                 const unsigned short* __restrict__ Wb,
                                                 const float* __restrict__ beff,
                                                 const float* __restrict__ fovp,
                                                 float* __restrict__ accPB,
                                                 float* __restrict__ cntB) {
  __shared__ float tile[64][132];
  __shared__ int sidx[64];
  int n = blockIdx.y;
  const unsigned short* A = P0b + (size_t)n * P0S;
  float* accP = accPB + (size_t)n * ACCS;
  float* cnt = cntB + (size_t)n * CNTS;
  int m0 = blockIdx.x * 64;
  int t = threadIdx.x;
  f32x4 acc[8];
  gemm16_mfma(A, Wb + 49152, m0 + (t >> 6) * 16, acc);
  if (t < 64) {
    int m = m0 + t;
    int j = m / 200, i = m - j * 200;
    float x, y;
    polar_xy(fovp[n], i, j, x, y);
    int xi = (int)rintf(x); xi = max(0, min(199, xi));
    int yi = (int)rintf(y); yi = max(0, min(199, yi));
    sidx[t] = yi * 200 + xi;
    atomicAdd(&cnt[yi * 200 + xi], 1.0f);
  }
  {
    int lane = t & 63, wv = t >> 6;
    int col = lane & 15, quad = lane >> 4;
#pragma unroll
    for (int nt = 0; nt < 8; ++nt) {
      float bb = beff[384 + nt * 16 + col];
#pragma unroll
      for (int r = 0; r < 4; ++r)
        tile[wv * 16 + quad * 4 + r][nt * 16 + col] = acc[nt][r] + bb;
    }
  }
  __syncthreads();
  int c = t & 127, half = t >> 7;
  int r0 = half * 32;
  int cur = sidx[r0];
  float sum = 0.0f;
#pragma unroll 4
  for (int r = r0; r < r0 + 32; ++r) {
    float v = tile[r][c];
    int idx = sidx[r];
    if (idx != cur) {
      atomicAdd(&accP[(size_t)cur * C1N + c], sum);
      cur = idx;
      sum = v;
    } else {
      sum += v;
    }
  }
  atomicAdd(&accP[(size_t)cur * C1N + c], sum);
}

// out = a + accP/cnt, both samples (grid (625, 2), y = n).
__global__ __launch_bounds__(256) void finalize2_k(const float* __restrict__ a,
                                                   const float* __restrict__ accPB,
                                                   const float* __restrict__ cntB,
                                                   float* __restrict__ out) {
  __shared__ float tile[64][129];
  __shared__ float sinv[64];
  int n = blockIdx.y;
  const float* an = a + (size_t)n * 5120000;
  const float* accP = accPB + (size_t)n * ACCS;
  const float* cnt = cntB + (size_t)n * CNTS;
  float* outn = out + (size_t)n * 5120000;
  int p0 = blockIdx.x * 64;
  int t = threadIdx.x;
  if (t < 64) {
    float cv = cnt[p0 + t];
    sinv[t] = 1.0f / (cv == 0.0f ? 1.0f : cv);
  }
  for (int u = t; u < 64 * 128; u += 256) {
    int pp = u >> 7, c = u & 127;
    tile[pp][c] = accP[(size_t)(p0 + pp) * C1N + c];
  }
  __syncthreads();
  for (int u = t; u < 64 * 128; u += 256) {
    int pp = u & 63, c = u >> 6;
    int g = c * 40000 + p0 + pp;
    outn[g] = an[g] + tile[pp][c] * sinv[pp];
  }
}

extern "C" void kernel_launch(void* const* d_in, const int* in_sizes, int n_in,
                              void* d_out, int out_size, void* d_ws, size_t ws_size,
                              hipStream_t stream) {
  const float* list_a = (const float*)d_in[0];
  const float* list_b = (const float*)d_in[1];
  const float* fov   = (const float*)d_in[2];
  const float* Wq    = (const float*)d_in[5];
  const float* bq    = (const float*)d_in[6];
  const float* Wk    = (const float*)d_in[7];
  const float* bk    = (const float*)d_in[8];
  const float* Wv    = (const float*)d_in[9];
  const float* bv    = (const float*)d_in[10];
  const float* inw   = (const float*)d_in[11];
  const float* inb   = (const float*)d_in[12];
  const float* outw  = (const float*)d_in[13];
  const float* outb  = (const float*)d_in[14];
  float* out = (float*)d_out;
  float* ws = (float*)d_ws;

  // Both-samples-batched layout (floats). Total 26,190,336 f = 104.8 MB
  // (old layout was 106.95 MB — fits the same workspace).
  //   beff 512 | Wb 32768 |
  //   S1 = P0_0, P0_1             (2 x 4,620,288 = 9,240,576; a_seq -> o)
  //   S2 = kb_0,vT_0,kb_1,vT_1    (4 x 2,949,120 = 11,796,480)
  //        -> after attn9: accP_0, accP_1 (2 x 5,120,000) + cnt_0, cnt_1
  //   S3 = aT_0, aT_1             (2 x 2,560,000 = 5,120,000)
  //        -> after bilinear: P1_0, P1_1 (2 x 2,310,144)
  // vT pads may hold stale accP garbage across launches: attn9 masks the
  // ks=6 pad keys IN-REGISTER, so no poison invariant is needed anymore.
  float* beff = ws;
  __hip_bfloat16* Wb = (__hip_bfloat16*)(ws + 512);
  float* S1f = ws + 33280;
  float* S2f = S1f + 9240576;
  float* S3f = S2f + 11796480;

  unsigned short* P0b = (unsigned short*)S1f;
  unsigned short* kbB = (unsigned short*)S2f;
  unsigned short* vTB = (unsigned short*)(S2f + 2949120);
  float* accPB = S2f;                 // after attn9 (kb/vT dead)
  float* cntB  = S2f + 2 * ACCS;      // 10,240,000 .. 10,320,000
  __hip_bfloat16* aTb = (__hip_bfloat16*)S3f;
  unsigned short* P1b = (unsigned short*)S3f;  // after bilinear (aT dead)

  weff_k<<<dim3(128, 4), 128, 0, stream>>>(Wq, Wk, Wv, bq, bk, bv, inw, inb, outw, outb, Wb, beff);

  transA_k<<<dim3(1250, 4, 2), 256, 0, stream>>>(list_a, aTb);
  bilinear2_k<<<dim3(GW, 10, 2), 256, 0, stream>>>(aTb, fov, (__hip_bfloat16*)P0b);
  // aT dead now; P1 overlays S3.
  transpose_k<<<dim3(24, 4, 100), 256, 0, stream>>>(list_b, (__hip_bfloat16*)P1b);
  gemm_kv_k<<<dim3(563, 2, 2), 256, 0, stream>>>(P1b, (const unsigned short*)Wb, beff, kbB, vTB);
  attn9_k<<<dim3(2520, 2), 512, 0, stream>>>(P0b, kbB, vTB,
                                             (const unsigned short*)Wb, beff);
  // kb/vT dead now; zero S2 as accP x2 + cnt x2.
  zero_k<<<2048, 256, 0, stream>>>(S2f);
  gemm_os_k<<<dim3(1125, 2), 256, 0, stream>>>(P0b, (const unsigned short*)Wb, beff,
                                               fov, accPB, cntB);
  finalize2_k<<<dim3(625, 2), 256, 0, stream>>>(list_a, accPB, cntB, out);
}